// Round 1
// baseline (8500.205 us; speedup 1.0000x reference)
//
#include <hip/hip_runtime.h>
#include <cstdint>
#include <cstddef>

static __device__ __forceinline__ float4 ld4(const float* p) {
    return *reinterpret_cast<const float4*>(p);
}

__global__ void deg_init_kernel(float* __restrict__ deg, int n) {
    int i = blockIdx.x * blockDim.x + threadIdx.x;
    if (i < n) deg[i] = 1.0f;   // self-loop contributes 1
}

__global__ void deg_scatter_kernel(const int* __restrict__ dst, float* __restrict__ deg, int e) {
    int i = blockIdx.x * blockDim.x + threadIdx.x;
    if (i < e) atomicAdd(&deg[dst[i]], 1.0f);
}

__global__ void dinv_kernel(float* __restrict__ deg, int n) {
    int i = blockIdx.x * blockDim.x + threadIdx.x;
    if (i < n) deg[i] = rsqrtf(deg[i]);   // deg >= 1 always
}

// H[N,128] = X[N,128] @ W[128,128], fp32, 128x128 block tile, 8x8 per thread
#define KC 32
__global__ __launch_bounds__(256)
void gemm128_kernel(const float* __restrict__ X, const float* __restrict__ W,
                    float* __restrict__ H, int n) {
    __shared__ float Xs[KC][132];   // transposed chunk: Xs[k][row], padded stride 132
    __shared__ float Ws[KC][128];
    const int t  = threadIdx.x;
    const int tx = t & 15;   // col group -> cols tx*8..+7
    const int ty = t >> 4;   // row group -> rows ty*8..+7
    const int row0 = blockIdx.x * 128;

    float acc[8][8];
#pragma unroll
    for (int i = 0; i < 8; ++i)
#pragma unroll
        for (int j = 0; j < 8; ++j) acc[i][j] = 0.0f;

    for (int kc = 0; kc < 128; kc += KC) {
        // stage X chunk (transposed into Xs[k][row])
#pragma unroll
        for (int jj = 0; jj < 4; ++jj) {
            int f  = t + jj * 256;       // float4 index, 0..1023
            int r  = f >> 3;             // 0..127
            int c4 = f & 7;              // 0..7
            int row = row0 + r;
            float4 v = make_float4(0.f, 0.f, 0.f, 0.f);
            if (row < n) v = ld4(X + (size_t)row * 128 + kc + c4 * 4);
            Xs[c4 * 4 + 0][r] = v.x;
            Xs[c4 * 4 + 1][r] = v.y;
            Xs[c4 * 4 + 2][r] = v.z;
            Xs[c4 * 4 + 3][r] = v.w;
        }
        // stage W chunk
#pragma unroll
        for (int jj = 0; jj < 4; ++jj) {
            int f  = t + jj * 256;
            int r  = f >> 5;             // 0..31
            int c4 = f & 31;             // 0..31
            float4 v = ld4(W + (size_t)(kc + r) * 128 + c4 * 4);
            *reinterpret_cast<float4*>(&Ws[r][c4 * 4]) = v;
        }
        __syncthreads();
#pragma unroll
        for (int k = 0; k < KC; ++k) {
            float4 x0 = ld4(&Xs[k][ty * 8]);
            float4 x1 = ld4(&Xs[k][ty * 8 + 4]);
            float4 w0 = ld4(&Ws[k][tx * 8]);
            float4 w1 = ld4(&Ws[k][tx * 8 + 4]);
            float xv[8] = {x0.x, x0.y, x0.z, x0.w, x1.x, x1.y, x1.z, x1.w};
            float wv[8] = {w0.x, w0.y, w0.z, w0.w, w1.x, w1.y, w1.z, w1.w};
#pragma unroll
            for (int i = 0; i < 8; ++i)
#pragma unroll
                for (int j = 0; j < 8; ++j)
                    acc[i][j] = fmaf(xv[i], wv[j], acc[i][j]);
        }
        __syncthreads();
    }
#pragma unroll
    for (int i = 0; i < 8; ++i) {
        int row = row0 + ty * 8 + i;
        if (row < n) {
            float4 o0 = make_float4(acc[i][0], acc[i][1], acc[i][2], acc[i][3]);
            float4 o1 = make_float4(acc[i][4], acc[i][5], acc[i][6], acc[i][7]);
            *reinterpret_cast<float4*>(H + (size_t)row * 128 + tx * 8)     = o0;
            *reinterpret_cast<float4*>(H + (size_t)row * 128 + tx * 8 + 4) = o1;
        }
    }
}

// 32 lanes per edge, float4 per lane: agg[dst] += dinv[src]*dinv[dst]*h[src]
__global__ void scatter_kernel(const int* __restrict__ src, const int* __restrict__ dst,
                               const float* __restrict__ dinv, const float* __restrict__ h,
                               float* __restrict__ agg, int e) {
    int gid  = blockIdx.x * blockDim.x + threadIdx.x;
    int ed   = gid >> 5;
    int lane = gid & 31;
    if (ed >= e) return;
    int s = src[ed];
    int d = dst[ed];
    float nrm = dinv[s] * dinv[d];
    float4 v = ld4(h + (size_t)s * 128 + lane * 4);
    float* ap = agg + (size_t)d * 128 + lane * 4;
    atomicAdd(ap + 0, nrm * v.x);
    atomicAdd(ap + 1, nrm * v.y);
    atomicAdd(ap + 2, nrm * v.z);
    atomicAdd(ap + 3, nrm * v.w);
}

// agg = maybe_relu(agg + dinv^2 * h + bias)   (self-loop + bias, dense)
__global__ void finish_kernel(float* __restrict__ agg, const float* __restrict__ h,
                              const float* __restrict__ dinv, const float* __restrict__ bias,
                              int n, int do_relu) {
    int gid  = blockIdx.x * blockDim.x + threadIdx.x;
    int i    = gid >> 5;
    int lane = gid & 31;
    if (i >= n) return;
    float di = dinv[i];
    float c  = di * di;
    size_t off = (size_t)i * 128 + lane * 4;
    float4 a  = ld4(agg + off);
    float4 hv = ld4(h + off);
    float4 b  = ld4(bias + lane * 4);
    a.x += c * hv.x + b.x;
    a.y += c * hv.y + b.y;
    a.z += c * hv.z + b.z;
    a.w += c * hv.w + b.w;
    if (do_relu) {
        a.x = fmaxf(a.x, 0.f); a.y = fmaxf(a.y, 0.f);
        a.z = fmaxf(a.z, 0.f); a.w = fmaxf(a.w, 0.f);
    }
    *reinterpret_cast<float4*>(agg + off) = a;
}

// batch is sorted: one block per graph, binary-search the node range, mean-pool
__global__ void pool_kernel(const float* __restrict__ h, const int* __restrict__ batch,
                            float* __restrict__ pooled, int n) {
    int g = blockIdx.x;
    int lo = 0, hi = n;
    while (lo < hi) { int mid = (lo + hi) >> 1; if (batch[mid] < g) lo = mid + 1; else hi = mid; }
    int start = lo;
    hi = n;
    while (lo < hi) { int mid = (lo + hi) >> 1; if (batch[mid] < g + 1) lo = mid + 1; else hi = mid; }
    int end = lo;
    int t = threadIdx.x;   // 128 threads = one feature each
    float acc = 0.f;
    for (int i = start; i < end; ++i) acc += h[(size_t)i * 128 + t];
    float cnt = (float)(end - start);
    pooled[g * 128 + t] = acc / fmaxf(cnt, 1.0f);
}

// out[g,c] = pooled[g,:] . Wl[:,c] + bl[c]
__global__ void final_kernel(const float* __restrict__ pooled, const float* __restrict__ Wl,
                             const float* __restrict__ bl, float* __restrict__ out, int n_classes) {
    __shared__ float ps[128];
    int g = blockIdx.x;
    int t = threadIdx.x;   // 64 threads
    ps[t]      = pooled[g * 128 + t];
    ps[t + 64] = pooled[g * 128 + 64 + t];
    __syncthreads();
    if (t < n_classes) {
        float acc = bl[t];
        for (int k = 0; k < 128; ++k)
            acc = fmaf(ps[k], Wl[k * n_classes + t], acc);
        out[g * n_classes + t] = acc;
    }
}

extern "C" void kernel_launch(void* const* d_in, const int* in_sizes, int n_in,
                              void* d_out, int out_size, void* d_ws, size_t ws_size,
                              hipStream_t stream) {
    const float* x     = (const float*)d_in[0];
    const int*   ei    = (const int*)d_in[1];
    const int*   batch = (const int*)d_in[2];
    const float* W1 = (const float*)d_in[3];
    const float* b1 = (const float*)d_in[4];
    const float* W2 = (const float*)d_in[5];
    const float* b2 = (const float*)d_in[6];
    const float* W3 = (const float*)d_in[7];
    const float* b3 = (const float*)d_in[8];
    const float* Wl = (const float*)d_in[9];
    const float* bl = (const float*)d_in[10];
    float* out = (float*)d_out;

    const int N = in_sizes[0] / 128;
    const int E = in_sizes[1] / 2;
    const int C = 10;
    const int G = out_size / C;

    const int* srcI = ei;
    const int* dstI = ei + E;

    char* w = (char*)d_ws;
    size_t off = 0;
    auto alloc = [&](size_t bytes) -> void* {
        void* p = w + off;
        off = (off + bytes + 255) & ~(size_t)255;
        return p;
    };
    float* dinv   = (float*)alloc((size_t)N * 4);
    float* bufA   = (float*)alloc((size_t)N * 128 * 4);
    float* bufB   = (float*)alloc((size_t)N * 128 * 4);
    float* pooled = (float*)alloc((size_t)G * 128 * 4);

    // degrees -> dinv
    deg_init_kernel<<<(N + 255) / 256, 256, 0, stream>>>(dinv, N);
    deg_scatter_kernel<<<(E + 255) / 256, 256, 0, stream>>>(dstI, dinv, E);
    dinv_kernel<<<(N + 255) / 256, 256, 0, stream>>>(dinv, N);

    const int gemmBlocks = (N + 127) / 128;
    const int scatBlocks = (E * 32 + 255) / 256;
    const int finBlocks  = (N * 32 + 255) / 256;
    const size_t featBytes = (size_t)N * 128 * 4;

    // ---- layer 1 ----
    gemm128_kernel<<<gemmBlocks, 256, 0, stream>>>(x, W1, bufA, N);
    hipMemsetAsync(bufB, 0, featBytes, stream);
    scatter_kernel<<<scatBlocks, 256, 0, stream>>>(srcI, dstI, dinv, bufA, bufB, E);
    finish_kernel<<<finBlocks, 256, 0, stream>>>(bufB, bufA, dinv, b1, N, 1);

    // ---- layer 2 ----
    gemm128_kernel<<<gemmBlocks, 256, 0, stream>>>(bufB, W2, bufA, N);
    hipMemsetAsync(bufB, 0, featBytes, stream);
    scatter_kernel<<<scatBlocks, 256, 0, stream>>>(srcI, dstI, dinv, bufA, bufB, E);
    finish_kernel<<<finBlocks, 256, 0, stream>>>(bufB, bufA, dinv, b2, N, 1);

    // ---- layer 3 ----
    gemm128_kernel<<<gemmBlocks, 256, 0, stream>>>(bufB, W3, bufA, N);
    hipMemsetAsync(bufB, 0, featBytes, stream);
    scatter_kernel<<<scatBlocks, 256, 0, stream>>>(srcI, dstI, dinv, bufA, bufB, E);
    finish_kernel<<<finBlocks, 256, 0, stream>>>(bufB, bufA, dinv, b3, N, 0);

    // ---- pool + classify ----
    pool_kernel<<<G, 128, 0, stream>>>(bufB, batch, pooled, N);
    final_kernel<<<G, 64, 0, stream>>>(pooled, Wl, bl, out, C);
}

// Round 2
// 959.548 us; speedup vs baseline: 8.8585x; 8.8585x over previous
//
#include <hip/hip_runtime.h>
#include <cstdint>
#include <cstddef>

static __device__ __forceinline__ float4 ld4(const float* p) {
    return *reinterpret_cast<const float4*>(p);
}

// ---------- CSR build ----------

__global__ void hist_kernel(const int* __restrict__ dst, int* __restrict__ cnt, int e) {
    int i = blockIdx.x * blockDim.x + threadIdx.x;
    if (i < e) atomicAdd(&cnt[dst[i]], 1);
}

// single block, 1024 threads: exclusive scan of cnt[0..n) -> rowptr[0..n]
__global__ __launch_bounds__(1024)
void scan_kernel(const int* __restrict__ cnt, int* __restrict__ rowptr, int n) {
    __shared__ int ls[1024];
    const int t = threadIdx.x;
    const int chunk = (n + 1023) >> 10;
    const int begin = t * chunk;
    const int endi  = min(begin + chunk, n);
    int s = 0;
    for (int i = begin; i < endi; ++i) s += cnt[i];
    ls[t] = s;
    __syncthreads();
    for (int off = 1; off < 1024; off <<= 1) {
        int v = (t >= off) ? ls[t - off] : 0;
        __syncthreads();
        ls[t] += v;
        __syncthreads();
    }
    int excl = (t == 0) ? 0 : ls[t - 1];
    for (int i = begin; i < endi; ++i) {
        rowptr[i] = excl;
        excl += cnt[i];
    }
    if (t == 1023) rowptr[n] = ls[1023];
}

// dinv[i] = rsqrt(in_degree + 1)   (self-loop included)
__global__ void dinv_kernel(const int* __restrict__ rowptr, float* __restrict__ dinv, int n) {
    int i = blockIdx.x * blockDim.x + threadIdx.x;
    if (i < n) dinv[i] = rsqrtf((float)(rowptr[i + 1] - rowptr[i] + 1));
}

__global__ void build_kernel(const int* __restrict__ src, const int* __restrict__ dst,
                             int* __restrict__ cursor, int* __restrict__ csr_src, int e) {
    int i = blockIdx.x * blockDim.x + threadIdx.x;
    if (i < e) {
        int pos = atomicAdd(&cursor[dst[i]], 1);
        csr_src[pos] = src[i];
    }
}

// ---------- GEMM: H[N,128] = X[N,128] @ W[128,128] ----------
#define KC 32
__global__ __launch_bounds__(256)
void gemm128_kernel(const float* __restrict__ X, const float* __restrict__ W,
                    float* __restrict__ H, int n) {
    __shared__ float Xs[KC][132];
    __shared__ float Ws[KC][128];
    const int t  = threadIdx.x;
    const int tx = t & 15;
    const int ty = t >> 4;
    const int row0 = blockIdx.x * 128;

    float acc[8][8];
#pragma unroll
    for (int i = 0; i < 8; ++i)
#pragma unroll
        for (int j = 0; j < 8; ++j) acc[i][j] = 0.0f;

    for (int kc = 0; kc < 128; kc += KC) {
#pragma unroll
        for (int jj = 0; jj < 4; ++jj) {
            int f  = t + jj * 256;
            int r  = f >> 3;
            int c4 = f & 7;
            int row = row0 + r;
            float4 v = make_float4(0.f, 0.f, 0.f, 0.f);
            if (row < n) v = ld4(X + (size_t)row * 128 + kc + c4 * 4);
            Xs[c4 * 4 + 0][r] = v.x;
            Xs[c4 * 4 + 1][r] = v.y;
            Xs[c4 * 4 + 2][r] = v.z;
            Xs[c4 * 4 + 3][r] = v.w;
        }
#pragma unroll
        for (int jj = 0; jj < 4; ++jj) {
            int f  = t + jj * 256;
            int r  = f >> 5;
            int c4 = f & 31;
            float4 v = ld4(W + (size_t)(kc + r) * 128 + c4 * 4);
            *reinterpret_cast<float4*>(&Ws[r][c4 * 4]) = v;
        }
        __syncthreads();
#pragma unroll
        for (int k = 0; k < KC; ++k) {
            float4 x0 = ld4(&Xs[k][ty * 8]);
            float4 x1 = ld4(&Xs[k][ty * 8 + 4]);
            float4 w0 = ld4(&Ws[k][tx * 8]);
            float4 w1 = ld4(&Ws[k][tx * 8 + 4]);
            float xv[8] = {x0.x, x0.y, x0.z, x0.w, x1.x, x1.y, x1.z, x1.w};
            float wv[8] = {w0.x, w0.y, w0.z, w0.w, w1.x, w1.y, w1.z, w1.w};
#pragma unroll
            for (int i = 0; i < 8; ++i)
#pragma unroll
                for (int j = 0; j < 8; ++j)
                    acc[i][j] = fmaf(xv[i], wv[j], acc[i][j]);
        }
        __syncthreads();
    }
#pragma unroll
    for (int i = 0; i < 8; ++i) {
        int row = row0 + ty * 8 + i;
        if (row < n) {
            float4 o0 = make_float4(acc[i][0], acc[i][1], acc[i][2], acc[i][3]);
            float4 o1 = make_float4(acc[i][4], acc[i][5], acc[i][6], acc[i][7]);
            *reinterpret_cast<float4*>(H + (size_t)row * 128 + tx * 8)     = o0;
            *reinterpret_cast<float4*>(H + (size_t)row * 128 + tx * 8 + 4) = o1;
        }
    }
}

// ---------- gather + self-loop + bias (+relu), fused ----------
// 32 lanes per dst node, float4 per lane
__global__ void gather_kernel(const int* __restrict__ rowptr, const int* __restrict__ csr_src,
                              const float* __restrict__ dinv, const float* __restrict__ h,
                              const float* __restrict__ bias, float* __restrict__ outb,
                              int n, int do_relu) {
    int gid  = blockIdx.x * blockDim.x + threadIdx.x;
    int node = gid >> 5;
    int lane = gid & 31;
    if (node >= n) return;

    int rs = rowptr[node];
    int re = rowptr[node + 1];
    float di = dinv[node];
    size_t base = (size_t)node * 128 + lane * 4;

    // self-loop: dinv[d]^2 * h[d]
    float4 hv = ld4(h + base);
    float c = di * di;
    float ax = c * hv.x, ay = c * hv.y, az = c * hv.z, aw = c * hv.w;

    for (int e0 = rs; e0 < re; e0 += 32) {
        int m = re - e0;
        if (m > 32) m = 32;
        int   sI = 0;
        float wI = 0.f;
        if (lane < m) {
            sI = csr_src[e0 + lane];
            wI = dinv[sI] * di;
        }
        int j = 0;
        for (; j + 1 < m; j += 2) {
            int   s0 = __shfl(sI, j, 32);
            float w0 = __shfl(wI, j, 32);
            int   s1 = __shfl(sI, j + 1, 32);
            float w1 = __shfl(wI, j + 1, 32);
            float4 v0 = ld4(h + (size_t)s0 * 128 + lane * 4);
            float4 v1 = ld4(h + (size_t)s1 * 128 + lane * 4);
            ax = fmaf(w0, v0.x, ax); ay = fmaf(w0, v0.y, ay);
            az = fmaf(w0, v0.z, az); aw = fmaf(w0, v0.w, aw);
            ax = fmaf(w1, v1.x, ax); ay = fmaf(w1, v1.y, ay);
            az = fmaf(w1, v1.z, az); aw = fmaf(w1, v1.w, aw);
        }
        if (j < m) {
            int   s0 = __shfl(sI, j, 32);
            float w0 = __shfl(wI, j, 32);
            float4 v0 = ld4(h + (size_t)s0 * 128 + lane * 4);
            ax = fmaf(w0, v0.x, ax); ay = fmaf(w0, v0.y, ay);
            az = fmaf(w0, v0.z, az); aw = fmaf(w0, v0.w, aw);
        }
    }

    float4 b = ld4(bias + lane * 4);
    ax += b.x; ay += b.y; az += b.z; aw += b.w;
    if (do_relu) {
        ax = fmaxf(ax, 0.f); ay = fmaxf(ay, 0.f);
        az = fmaxf(az, 0.f); aw = fmaxf(aw, 0.f);
    }
    float4 o = make_float4(ax, ay, az, aw);
    *reinterpret_cast<float4*>(outb + base) = o;
}

// ---------- pooling + classifier ----------

__global__ void pool_kernel(const float* __restrict__ h, const int* __restrict__ batch,
                            float* __restrict__ pooled, int n) {
    int g = blockIdx.x;
    int lo = 0, hi = n;
    while (lo < hi) { int mid = (lo + hi) >> 1; if (batch[mid] < g) lo = mid + 1; else hi = mid; }
    int start = lo;
    hi = n;
    while (lo < hi) { int mid = (lo + hi) >> 1; if (batch[mid] < g + 1) lo = mid + 1; else hi = mid; }
    int end = lo;
    int t = threadIdx.x;
    float acc = 0.f;
    for (int i = start; i < end; ++i) acc += h[(size_t)i * 128 + t];
    float cnt = (float)(end - start);
    pooled[g * 128 + t] = acc / fmaxf(cnt, 1.0f);
}

__global__ void final_kernel(const float* __restrict__ pooled, const float* __restrict__ Wl,
                             const float* __restrict__ bl, float* __restrict__ out, int n_classes) {
    __shared__ float ps[128];
    int g = blockIdx.x;
    int t = threadIdx.x;
    ps[t]      = pooled[g * 128 + t];
    ps[t + 64] = pooled[g * 128 + 64 + t];
    __syncthreads();
    if (t < n_classes) {
        float acc = bl[t];
        for (int k = 0; k < 128; ++k)
            acc = fmaf(ps[k], Wl[k * n_classes + t], acc);
        out[g * n_classes + t] = acc;
    }
}

extern "C" void kernel_launch(void* const* d_in, const int* in_sizes, int n_in,
                              void* d_out, int out_size, void* d_ws, size_t ws_size,
                              hipStream_t stream) {
    const float* x     = (const float*)d_in[0];
    const int*   ei    = (const int*)d_in[1];
    const int*   batch = (const int*)d_in[2];
    const float* W1 = (const float*)d_in[3];
    const float* b1 = (const float*)d_in[4];
    const float* W2 = (const float*)d_in[5];
    const float* b2 = (const float*)d_in[6];
    const float* W3 = (const float*)d_in[7];
    const float* b3 = (const float*)d_in[8];
    const float* Wl = (const float*)d_in[9];
    const float* bl = (const float*)d_in[10];
    float* out = (float*)d_out;

    const int N = in_sizes[0] / 128;
    const int E = in_sizes[1] / 2;
    const int C = 10;
    const int G = out_size / C;

    const int* srcI = ei;
    const int* dstI = ei + E;

    char* w = (char*)d_ws;
    size_t off = 0;
    auto alloc = [&](size_t bytes) -> void* {
        void* p = w + off;
        off = (off + bytes + 255) & ~(size_t)255;
        return p;
    };
    int*   cnt     = (int*)alloc((size_t)N * 4);          // histogram, then reused as cursor
    int*   rowptr  = (int*)alloc((size_t)(N + 1) * 4);
    float* dinv    = (float*)alloc((size_t)N * 4);
    int*   csr_src = (int*)alloc((size_t)E * 4);
    float* bufA    = (float*)alloc((size_t)N * 128 * 4);
    float* bufB    = (float*)alloc((size_t)N * 128 * 4);
    float* pooled  = (float*)alloc((size_t)G * 128 * 4);

    // ---- CSR build (once) ----
    hipMemsetAsync(cnt, 0, (size_t)N * 4, stream);
    hist_kernel<<<(E + 255) / 256, 256, 0, stream>>>(dstI, cnt, E);
    scan_kernel<<<1, 1024, 0, stream>>>(cnt, rowptr, N);
    dinv_kernel<<<(N + 255) / 256, 256, 0, stream>>>(rowptr, dinv, N);
    // cnt becomes the insertion cursor
    hipMemcpyAsync(cnt, rowptr, (size_t)N * 4, hipMemcpyDeviceToDevice, stream);
    build_kernel<<<(E + 255) / 256, 256, 0, stream>>>(srcI, dstI, cnt, csr_src, E);

    const int gemmBlocks = (N + 127) / 128;
    const int gathBlocks = (N * 32 + 255) / 256;

    // ---- layer 1 ----
    gemm128_kernel<<<gemmBlocks, 256, 0, stream>>>(x, W1, bufA, N);
    gather_kernel<<<gathBlocks, 256, 0, stream>>>(rowptr, csr_src, dinv, bufA, b1, bufB, N, 1);
    // ---- layer 2 ----
    gemm128_kernel<<<gemmBlocks, 256, 0, stream>>>(bufB, W2, bufA, N);
    gather_kernel<<<gathBlocks, 256, 0, stream>>>(rowptr, csr_src, dinv, bufA, b2, bufB, N, 1);
    // ---- layer 3 ----
    gemm128_kernel<<<gemmBlocks, 256, 0, stream>>>(bufB, W3, bufA, N);
    gather_kernel<<<gathBlocks, 256, 0, stream>>>(rowptr, csr_src, dinv, bufA, b3, bufB, N, 0);

    // ---- pool + classify ----
    pool_kernel<<<G, 128, 0, stream>>>(bufB, batch, pooled, N);
    final_kernel<<<G, 64, 0, stream>>>(pooled, Wl, bl, out, C);
}

// Round 3
// 809.565 us; speedup vs baseline: 10.4997x; 1.1853x over previous
//
#include <hip/hip_runtime.h>
#include <cstdint>
#include <cstddef>

static __device__ __forceinline__ float4 ld4(const float* p) {
    return *reinterpret_cast<const float4*>(p);
}

// ---------- CSR build ----------

__global__ void hist_kernel(const int* __restrict__ dst, int* __restrict__ cnt, int e) {
    int i = blockIdx.x * blockDim.x + threadIdx.x;
    if (i < e) atomicAdd(&cnt[dst[i]], 1);
}

// Pass 1: per-block sums of 1024 counts (256 threads x int4)
__global__ __launch_bounds__(256)
void scan1_kernel(const int* __restrict__ cnt, int* __restrict__ blockSums, int n) {
    __shared__ int ts[256];
    const int t = threadIdx.x;
    const int base = blockIdx.x * 1024 + t * 4;
    int s = 0;
    if (base + 3 < n) {
        int4 q = *reinterpret_cast<const int4*>(cnt + base);
        s = q.x + q.y + q.z + q.w;
    } else {
#pragma unroll
        for (int j = 0; j < 4; ++j) if (base + j < n) s += cnt[base + j];
    }
    ts[t] = s;
    __syncthreads();
    for (int off = 128; off > 0; off >>= 1) {
        if (t < off) ts[t] += ts[t + off];
        __syncthreads();
    }
    if (t == 0) blockSums[blockIdx.x] = ts[0];
}

// Pass 2: one block scans the block sums (nb <= 1024) -> exclusive offsets + total
__global__ __launch_bounds__(1024)
void scan_top_kernel(const int* __restrict__ blockSums, int* __restrict__ blockOff,
                     int* __restrict__ rowptr_total, int nb) {
    __shared__ int ls[1024];
    const int t = threadIdx.x;
    ls[t] = (t < nb) ? blockSums[t] : 0;
    __syncthreads();
    for (int off = 1; off < 1024; off <<= 1) {
        int v = (t >= off) ? ls[t - off] : 0;
        __syncthreads();
        ls[t] += v;
        __syncthreads();
    }
    if (t < nb) blockOff[t] = (t == 0) ? 0 : ls[t - 1];
    if (t == 1023) rowptr_total[0] = ls[1023];
}

// Pass 3: per-block exclusive scan of 1024 counts + block offset -> rowptr[0..n)
__global__ __launch_bounds__(256)
void scan2_kernel(const int* __restrict__ cnt, const int* __restrict__ blockOff,
                  int* __restrict__ rowptr, int n) {
    __shared__ int ts[256];
    const int t = threadIdx.x;
    const int base = blockIdx.x * 1024 + t * 4;
    int v[4] = {0, 0, 0, 0};
    if (base + 3 < n) {
        int4 q = *reinterpret_cast<const int4*>(cnt + base);
        v[0] = q.x; v[1] = q.y; v[2] = q.z; v[3] = q.w;
    } else {
#pragma unroll
        for (int j = 0; j < 4; ++j) if (base + j < n) v[j] = cnt[base + j];
    }
    int s = v[0] + v[1] + v[2] + v[3];
    ts[t] = s;
    __syncthreads();
    for (int off = 1; off < 256; off <<= 1) {
        int x = (t >= off) ? ts[t - off] : 0;
        __syncthreads();
        ts[t] += x;
        __syncthreads();
    }
    int excl = blockOff[blockIdx.x] + ((t == 0) ? 0 : ts[t - 1]);
#pragma unroll
    for (int j = 0; j < 4; ++j) {
        if (base + j < n) rowptr[base + j] = excl;
        excl += v[j];
    }
}

// dinv[i] = rsqrt(in_degree + 1)   (self-loop included)
__global__ void dinv_kernel(const int* __restrict__ rowptr, float* __restrict__ dinv, int n) {
    int i = blockIdx.x * blockDim.x + threadIdx.x;
    if (i < n) dinv[i] = rsqrtf((float)(rowptr[i + 1] - rowptr[i] + 1));
}

__global__ void build_kernel(const int* __restrict__ src, const int* __restrict__ dst,
                             int* __restrict__ cursor, int* __restrict__ csr_src, int e) {
    int i = blockIdx.x * blockDim.x + threadIdx.x;
    if (i < e) {
        int pos = atomicAdd(&cursor[dst[i]], 1);
        csr_src[pos] = src[i];
    }
}

// ---------- GEMM: H[N,128] = X[N,128] @ W[128,128] ----------
#define KC 32
__global__ __launch_bounds__(256)
void gemm128_kernel(const float* __restrict__ X, const float* __restrict__ W,
                    float* __restrict__ H, int n) {
    __shared__ float Xs[KC][132];
    __shared__ float Ws[KC][128];
    const int t  = threadIdx.x;
    const int tx = t & 15;
    const int ty = t >> 4;
    const int row0 = blockIdx.x * 128;

    float acc[8][8];
#pragma unroll
    for (int i = 0; i < 8; ++i)
#pragma unroll
        for (int j = 0; j < 8; ++j) acc[i][j] = 0.0f;

    for (int kc = 0; kc < 128; kc += KC) {
#pragma unroll
        for (int jj = 0; jj < 4; ++jj) {
            int f  = t + jj * 256;
            int r  = f >> 3;
            int c4 = f & 7;
            int row = row0 + r;
            float4 v = make_float4(0.f, 0.f, 0.f, 0.f);
            if (row < n) v = ld4(X + (size_t)row * 128 + kc + c4 * 4);
            Xs[c4 * 4 + 0][r] = v.x;
            Xs[c4 * 4 + 1][r] = v.y;
            Xs[c4 * 4 + 2][r] = v.z;
            Xs[c4 * 4 + 3][r] = v.w;
        }
#pragma unroll
        for (int jj = 0; jj < 4; ++jj) {
            int f  = t + jj * 256;
            int r  = f >> 5;
            int c4 = f & 31;
            float4 v = ld4(W + (size_t)(kc + r) * 128 + c4 * 4);
            *reinterpret_cast<float4*>(&Ws[r][c4 * 4]) = v;
        }
        __syncthreads();
#pragma unroll
        for (int k = 0; k < KC; ++k) {
            float4 x0 = ld4(&Xs[k][ty * 8]);
            float4 x1 = ld4(&Xs[k][ty * 8 + 4]);
            float4 w0 = ld4(&Ws[k][tx * 8]);
            float4 w1 = ld4(&Ws[k][tx * 8 + 4]);
            float xv[8] = {x0.x, x0.y, x0.z, x0.w, x1.x, x1.y, x1.z, x1.w};
            float wv[8] = {w0.x, w0.y, w0.z, w0.w, w1.x, w1.y, w1.z, w1.w};
#pragma unroll
            for (int i = 0; i < 8; ++i)
#pragma unroll
                for (int j = 0; j < 8; ++j)
                    acc[i][j] = fmaf(xv[i], wv[j], acc[i][j]);
        }
        __syncthreads();
    }
#pragma unroll
    for (int i = 0; i < 8; ++i) {
        int row = row0 + ty * 8 + i;
        if (row < n) {
            float4 o0 = make_float4(acc[i][0], acc[i][1], acc[i][2], acc[i][3]);
            float4 o1 = make_float4(acc[i][4], acc[i][5], acc[i][6], acc[i][7]);
            *reinterpret_cast<float4*>(H + (size_t)row * 128 + tx * 8)     = o0;
            *reinterpret_cast<float4*>(H + (size_t)row * 128 + tx * 8 + 4) = o1;
        }
    }
}

// ---------- gather + self-loop + bias (+relu), fused ----------
__global__ void gather_kernel(const int* __restrict__ rowptr, const int* __restrict__ csr_src,
                              const float* __restrict__ dinv, const float* __restrict__ h,
                              const float* __restrict__ bias, float* __restrict__ outb,
                              int n, int do_relu) {
    int gid  = blockIdx.x * blockDim.x + threadIdx.x;
    int node = gid >> 5;
    int lane = gid & 31;
    if (node >= n) return;

    int rs = rowptr[node];
    int re = rowptr[node + 1];
    float di = dinv[node];
    size_t base = (size_t)node * 128 + lane * 4;

    float4 hv = ld4(h + base);
    float c = di * di;
    float ax = c * hv.x, ay = c * hv.y, az = c * hv.z, aw = c * hv.w;

    for (int e0 = rs; e0 < re; e0 += 32) {
        int m = re - e0;
        if (m > 32) m = 32;
        int   sI = 0;
        float wI = 0.f;
        if (lane < m) {
            sI = csr_src[e0 + lane];
            wI = dinv[sI] * di;
        }
        int j = 0;
        for (; j + 1 < m; j += 2) {
            int   s0 = __shfl(sI, j, 32);
            float w0 = __shfl(wI, j, 32);
            int   s1 = __shfl(sI, j + 1, 32);
            float w1 = __shfl(wI, j + 1, 32);
            float4 v0 = ld4(h + (size_t)s0 * 128 + lane * 4);
            float4 v1 = ld4(h + (size_t)s1 * 128 + lane * 4);
            ax = fmaf(w0, v0.x, ax); ay = fmaf(w0, v0.y, ay);
            az = fmaf(w0, v0.z, az); aw = fmaf(w0, v0.w, aw);
            ax = fmaf(w1, v1.x, ax); ay = fmaf(w1, v1.y, ay);
            az = fmaf(w1, v1.z, az); aw = fmaf(w1, v1.w, aw);
        }
        if (j < m) {
            int   s0 = __shfl(sI, j, 32);
            float w0 = __shfl(wI, j, 32);
            float4 v0 = ld4(h + (size_t)s0 * 128 + lane * 4);
            ax = fmaf(w0, v0.x, ax); ay = fmaf(w0, v0.y, ay);
            az = fmaf(w0, v0.z, az); aw = fmaf(w0, v0.w, aw);
        }
    }

    float4 b = ld4(bias + lane * 4);
    ax += b.x; ay += b.y; az += b.z; aw += b.w;
    if (do_relu) {
        ax = fmaxf(ax, 0.f); ay = fmaxf(ay, 0.f);
        az = fmaxf(az, 0.f); aw = fmaxf(aw, 0.f);
    }
    float4 o = make_float4(ax, ay, az, aw);
    *reinterpret_cast<float4*>(outb + base) = o;
}

// ---------- pooling + classifier ----------

__global__ void pool_kernel(const float* __restrict__ h, const int* __restrict__ batch,
                            float* __restrict__ pooled, int n) {
    int g = blockIdx.x;
    int lo = 0, hi = n;
    while (lo < hi) { int mid = (lo + hi) >> 1; if (batch[mid] < g) lo = mid + 1; else hi = mid; }
    int start = lo;
    hi = n;
    while (lo < hi) { int mid = (lo + hi) >> 1; if (batch[mid] < g + 1) lo = mid + 1; else hi = mid; }
    int end = lo;
    int t = threadIdx.x;
    float acc = 0.f;
    for (int i = start; i < end; ++i) acc += h[(size_t)i * 128 + t];
    float cnt = (float)(end - start);
    pooled[g * 128 + t] = acc / fmaxf(cnt, 1.0f);
}

__global__ void final_kernel(const float* __restrict__ pooled, const float* __restrict__ Wl,
                             const float* __restrict__ bl, float* __restrict__ out, int n_classes) {
    __shared__ float ps[128];
    int g = blockIdx.x;
    int t = threadIdx.x;
    ps[t]      = pooled[g * 128 + t];
    ps[t + 64] = pooled[g * 128 + 64 + t];
    __syncthreads();
    if (t < n_classes) {
        float acc = bl[t];
        for (int k = 0; k < 128; ++k)
            acc = fmaf(ps[k], Wl[k * n_classes + t], acc);
        out[g * n_classes + t] = acc;
    }
}

extern "C" void kernel_launch(void* const* d_in, const int* in_sizes, int n_in,
                              void* d_out, int out_size, void* d_ws, size_t ws_size,
                              hipStream_t stream) {
    const float* x     = (const float*)d_in[0];
    const int*   ei    = (const int*)d_in[1];
    const int*   batch = (const int*)d_in[2];
    const float* W1 = (const float*)d_in[3];
    const float* b1 = (const float*)d_in[4];
    const float* W2 = (const float*)d_in[5];
    const float* b2 = (const float*)d_in[6];
    const float* W3 = (const float*)d_in[7];
    const float* b3 = (const float*)d_in[8];
    const float* Wl = (const float*)d_in[9];
    const float* bl = (const float*)d_in[10];
    float* out = (float*)d_out;

    const int N = in_sizes[0] / 128;
    const int E = in_sizes[1] / 2;
    const int C = 10;
    const int G = out_size / C;

    const int* srcI = ei;
    const int* dstI = ei + E;

    char* w = (char*)d_ws;
    size_t off = 0;
    auto alloc = [&](size_t bytes) -> void* {
        void* p = w + off;
        off = (off + bytes + 255) & ~(size_t)255;
        return p;
    };
    const int scanBlocks = (N + 1023) / 1024;

    int*   cnt       = (int*)alloc((size_t)N * 4);
    int*   rowptr    = (int*)alloc((size_t)(N + 1) * 4);
    float* dinv      = (float*)alloc((size_t)N * 4);
    int*   csr_src   = (int*)alloc((size_t)E * 4);
    int*   blockSums = (int*)alloc((size_t)scanBlocks * 4);
    int*   blockOff  = (int*)alloc((size_t)scanBlocks * 4);
    float* bufA      = (float*)alloc((size_t)N * 128 * 4);
    float* bufB      = (float*)alloc((size_t)N * 128 * 4);
    float* pooled    = (float*)alloc((size_t)G * 128 * 4);

    // ---- CSR build (once) ----
    hipMemsetAsync(cnt, 0, (size_t)N * 4, stream);
    hist_kernel<<<(E + 255) / 256, 256, 0, stream>>>(dstI, cnt, E);
    scan1_kernel<<<scanBlocks, 256, 0, stream>>>(cnt, blockSums, N);
    scan_top_kernel<<<1, 1024, 0, stream>>>(blockSums, blockOff, rowptr + N, scanBlocks);
    scan2_kernel<<<scanBlocks, 256, 0, stream>>>(cnt, blockOff, rowptr, N);
    dinv_kernel<<<(N + 255) / 256, 256, 0, stream>>>(rowptr, dinv, N);
    hipMemcpyAsync(cnt, rowptr, (size_t)N * 4, hipMemcpyDeviceToDevice, stream);
    build_kernel<<<(E + 255) / 256, 256, 0, stream>>>(srcI, dstI, cnt, csr_src, E);

    const int gemmBlocks = (N + 127) / 128;
    const int gathBlocks = (N * 32 + 255) / 256;

    // ---- layer 1 ----
    gemm128_kernel<<<gemmBlocks, 256, 0, stream>>>(x, W1, bufA, N);
    gather_kernel<<<gathBlocks, 256, 0, stream>>>(rowptr, csr_src, dinv, bufA, b1, bufB, N, 1);
    // ---- layer 2 ----
    gemm128_kernel<<<gemmBlocks, 256, 0, stream>>>(bufB, W2, bufA, N);
    gather_kernel<<<gathBlocks, 256, 0, stream>>>(rowptr, csr_src, dinv, bufA, b2, bufB, N, 1);
    // ---- layer 3 ----
    gemm128_kernel<<<gemmBlocks, 256, 0, stream>>>(bufB, W3, bufA, N);
    gather_kernel<<<gathBlocks, 256, 0, stream>>>(rowptr, csr_src, dinv, bufA, b3, bufB, N, 0);

    // ---- pool + classify ----
    pool_kernel<<<G, 128, 0, stream>>>(bufB, batch, pooled, N);
    final_kernel<<<G, 64, 0, stream>>>(pooled, Wl, bl, out, C);
}

// Round 4
// 610.544 us; speedup vs baseline: 13.9224x; 1.3260x over previous
//
#include <hip/hip_runtime.h>
#include <hip/hip_fp16.h>
#include <cstdint>
#include <cstddef>

static __device__ __forceinline__ float4 ld4(const float* p) {
    return *reinterpret_cast<const float4*>(p);
}

// load 8 halves (16B) -> 8 floats
static __device__ __forceinline__ void ld8h(const __half* p, float* f) {
    uint4 q = *reinterpret_cast<const uint4*>(p);
    __half2 h0 = *reinterpret_cast<__half2*>(&q.x);
    __half2 h1 = *reinterpret_cast<__half2*>(&q.y);
    __half2 h2 = *reinterpret_cast<__half2*>(&q.z);
    __half2 h3 = *reinterpret_cast<__half2*>(&q.w);
    float2 a = __half22float2(h0); f[0] = a.x; f[1] = a.y;
    float2 b = __half22float2(h1); f[2] = b.x; f[3] = b.y;
    float2 c = __half22float2(h2); f[4] = c.x; f[5] = c.y;
    float2 d = __half22float2(h3); f[6] = d.x; f[7] = d.y;
}

// ---------- CSR build ----------

__global__ void hist_kernel(const int* __restrict__ dst, int* __restrict__ cnt, int e) {
    int i = blockIdx.x * blockDim.x + threadIdx.x;
    if (i < e) atomicAdd(&cnt[dst[i]], 1);
}

__global__ __launch_bounds__(256)
void scan1_kernel(const int* __restrict__ cnt, int* __restrict__ blockSums, int n) {
    __shared__ int ts[256];
    const int t = threadIdx.x;
    const int base = blockIdx.x * 1024 + t * 4;
    int s = 0;
    if (base + 3 < n) {
        int4 q = *reinterpret_cast<const int4*>(cnt + base);
        s = q.x + q.y + q.z + q.w;
    } else {
#pragma unroll
        for (int j = 0; j < 4; ++j) if (base + j < n) s += cnt[base + j];
    }
    ts[t] = s;
    __syncthreads();
    for (int off = 128; off > 0; off >>= 1) {
        if (t < off) ts[t] += ts[t + off];
        __syncthreads();
    }
    if (t == 0) blockSums[blockIdx.x] = ts[0];
}

__global__ __launch_bounds__(1024)
void scan_top_kernel(const int* __restrict__ blockSums, int* __restrict__ blockOff,
                     int* __restrict__ rowptr_total, int nb) {
    __shared__ int ls[1024];
    const int t = threadIdx.x;
    ls[t] = (t < nb) ? blockSums[t] : 0;
    __syncthreads();
    for (int off = 1; off < 1024; off <<= 1) {
        int v = (t >= off) ? ls[t - off] : 0;
        __syncthreads();
        ls[t] += v;
        __syncthreads();
    }
    if (t < nb) blockOff[t] = (t == 0) ? 0 : ls[t - 1];
    if (t == 1023) rowptr_total[0] = ls[1023];
}

__global__ __launch_bounds__(256)
void scan2_kernel(const int* __restrict__ cnt, const int* __restrict__ blockOff,
                  int* __restrict__ rowptr, int n) {
    __shared__ int ts[256];
    const int t = threadIdx.x;
    const int base = blockIdx.x * 1024 + t * 4;
    int v[4] = {0, 0, 0, 0};
    if (base + 3 < n) {
        int4 q = *reinterpret_cast<const int4*>(cnt + base);
        v[0] = q.x; v[1] = q.y; v[2] = q.z; v[3] = q.w;
    } else {
#pragma unroll
        for (int j = 0; j < 4; ++j) if (base + j < n) v[j] = cnt[base + j];
    }
    int s = v[0] + v[1] + v[2] + v[3];
    ts[t] = s;
    __syncthreads();
    for (int off = 1; off < 256; off <<= 1) {
        int x = (t >= off) ? ts[t - off] : 0;
        __syncthreads();
        ts[t] += x;
        __syncthreads();
    }
    int excl = blockOff[blockIdx.x] + ((t == 0) ? 0 : ts[t - 1]);
#pragma unroll
    for (int j = 0; j < 4; ++j) {
        if (base + j < n) rowptr[base + j] = excl;
        excl += v[j];
    }
}

__global__ void dinv_kernel(const int* __restrict__ rowptr, float* __restrict__ dinv, int n) {
    int i = blockIdx.x * blockDim.x + threadIdx.x;
    if (i < n) dinv[i] = rsqrtf((float)(rowptr[i + 1] - rowptr[i] + 1));
}

// bucket edges by dst; also precompute per-edge weight dinv[s]*dinv[d]
__global__ void build_kernel(const int* __restrict__ src, const int* __restrict__ dst,
                             const float* __restrict__ dinv,
                             int* __restrict__ cursor, int* __restrict__ csr_src,
                             float* __restrict__ csr_w, int e) {
    int i = blockIdx.x * blockDim.x + threadIdx.x;
    if (i < e) {
        int s = src[i];
        int d = dst[i];
        int pos = atomicAdd(&cursor[d], 1);
        csr_src[pos] = s;
        csr_w[pos] = dinv[s] * dinv[d];
    }
}

// ---------- GEMM: H16[N,128] = fp16( X[N,128] @ W[128,128] ) ----------
#define KC 32
__global__ __launch_bounds__(256)
void gemm128_kernel(const float* __restrict__ X, const float* __restrict__ W,
                    __half* __restrict__ H16, int n) {
    __shared__ float Xs[KC][132];
    __shared__ float Ws[KC][128];
    const int t  = threadIdx.x;
    const int tx = t & 15;
    const int ty = t >> 4;
    const int row0 = blockIdx.x * 128;

    float acc[8][8];
#pragma unroll
    for (int i = 0; i < 8; ++i)
#pragma unroll
        for (int j = 0; j < 8; ++j) acc[i][j] = 0.0f;

    for (int kc = 0; kc < 128; kc += KC) {
#pragma unroll
        for (int jj = 0; jj < 4; ++jj) {
            int f  = t + jj * 256;
            int r  = f >> 3;
            int c4 = f & 7;
            int row = row0 + r;
            float4 v = make_float4(0.f, 0.f, 0.f, 0.f);
            if (row < n) v = ld4(X + (size_t)row * 128 + kc + c4 * 4);
            Xs[c4 * 4 + 0][r] = v.x;
            Xs[c4 * 4 + 1][r] = v.y;
            Xs[c4 * 4 + 2][r] = v.z;
            Xs[c4 * 4 + 3][r] = v.w;
        }
#pragma unroll
        for (int jj = 0; jj < 4; ++jj) {
            int f  = t + jj * 256;
            int r  = f >> 5;
            int c4 = f & 31;
            float4 v = ld4(W + (size_t)(kc + r) * 128 + c4 * 4);
            *reinterpret_cast<float4*>(&Ws[r][c4 * 4]) = v;
        }
        __syncthreads();
#pragma unroll
        for (int k = 0; k < KC; ++k) {
            float4 x0 = ld4(&Xs[k][ty * 8]);
            float4 x1 = ld4(&Xs[k][ty * 8 + 4]);
            float4 w0 = ld4(&Ws[k][tx * 8]);
            float4 w1 = ld4(&Ws[k][tx * 8 + 4]);
            float xv[8] = {x0.x, x0.y, x0.z, x0.w, x1.x, x1.y, x1.z, x1.w};
            float wv[8] = {w0.x, w0.y, w0.z, w0.w, w1.x, w1.y, w1.z, w1.w};
#pragma unroll
            for (int i = 0; i < 8; ++i)
#pragma unroll
                for (int j = 0; j < 8; ++j)
                    acc[i][j] = fmaf(xv[i], wv[j], acc[i][j]);
        }
        __syncthreads();
    }
#pragma unroll
    for (int i = 0; i < 8; ++i) {
        int row = row0 + ty * 8 + i;
        if (row < n) {
            __half2 p0 = __floats2half2_rn(acc[i][0], acc[i][1]);
            __half2 p1 = __floats2half2_rn(acc[i][2], acc[i][3]);
            __half2 p2 = __floats2half2_rn(acc[i][4], acc[i][5]);
            __half2 p3 = __floats2half2_rn(acc[i][6], acc[i][7]);
            uint4 q;
            q.x = *reinterpret_cast<unsigned int*>(&p0);
            q.y = *reinterpret_cast<unsigned int*>(&p1);
            q.z = *reinterpret_cast<unsigned int*>(&p2);
            q.w = *reinterpret_cast<unsigned int*>(&p3);
            *reinterpret_cast<uint4*>(H16 + (size_t)row * 128 + tx * 8) = q;
        }
    }
}

// ---------- gather (fp16 rows) + self-loop + bias (+relu), fused ----------
// 16 lanes per dst node, 8 features (16B fp16) per lane
__global__ __launch_bounds__(256)
void gather_kernel(const int* __restrict__ rowptr, const int* __restrict__ csr_src,
                   const float* __restrict__ csr_w, const float* __restrict__ dinv,
                   const __half* __restrict__ h16, const float* __restrict__ bias,
                   float* __restrict__ outb, int n, int do_relu) {
    int gid  = blockIdx.x * blockDim.x + threadIdx.x;
    int node = gid >> 4;
    int lane = gid & 15;
    if (node >= n) return;

    int rs = rowptr[node];
    int re = rowptr[node + 1];
    float di = dinv[node];
    const int fo = lane * 8;

    float acc[8];
    {
        float f[8];
        ld8h(h16 + (size_t)node * 128 + fo, f);
        float c = di * di;
#pragma unroll
        for (int k = 0; k < 8; ++k) acc[k] = c * f[k];
    }

    for (int e0 = rs; e0 < re; e0 += 16) {
        int m = re - e0;
        if (m > 16) m = 16;
        int   sI = 0;
        float wI = 0.f;
        if (lane < m) {
            sI = csr_src[e0 + lane];
            wI = csr_w[e0 + lane];
        }
        int j = 0;
        for (; j + 1 < m; j += 2) {
            int   s0 = __shfl(sI, j, 16);
            float w0 = __shfl(wI, j, 16);
            int   s1 = __shfl(sI, j + 1, 16);
            float w1 = __shfl(wI, j + 1, 16);
            float f0[8], f1[8];
            ld8h(h16 + (size_t)s0 * 128 + fo, f0);
            ld8h(h16 + (size_t)s1 * 128 + fo, f1);
#pragma unroll
            for (int k = 0; k < 8; ++k) {
                acc[k] = fmaf(w0, f0[k], acc[k]);
                acc[k] = fmaf(w1, f1[k], acc[k]);
            }
        }
        if (j < m) {
            int   s0 = __shfl(sI, j, 16);
            float w0 = __shfl(wI, j, 16);
            float f0[8];
            ld8h(h16 + (size_t)s0 * 128 + fo, f0);
#pragma unroll
            for (int k = 0; k < 8; ++k) acc[k] = fmaf(w0, f0[k], acc[k]);
        }
    }

    float4 b0 = ld4(bias + fo);
    float4 b1 = ld4(bias + fo + 4);
    acc[0] += b0.x; acc[1] += b0.y; acc[2] += b0.z; acc[3] += b0.w;
    acc[4] += b1.x; acc[5] += b1.y; acc[6] += b1.z; acc[7] += b1.w;
    if (do_relu) {
#pragma unroll
        for (int k = 0; k < 8; ++k) acc[k] = fmaxf(acc[k], 0.f);
    }
    float* op = outb + (size_t)node * 128 + fo;
    *reinterpret_cast<float4*>(op)     = make_float4(acc[0], acc[1], acc[2], acc[3]);
    *reinterpret_cast<float4*>(op + 4) = make_float4(acc[4], acc[5], acc[6], acc[7]);
}

// ---------- pooling + classifier ----------

__global__ void pool_kernel(const float* __restrict__ h, const int* __restrict__ batch,
                            float* __restrict__ pooled, int n) {
    int g = blockIdx.x;
    int lo = 0, hi = n;
    while (lo < hi) { int mid = (lo + hi) >> 1; if (batch[mid] < g) lo = mid + 1; else hi = mid; }
    int start = lo;
    hi = n;
    while (lo < hi) { int mid = (lo + hi) >> 1; if (batch[mid] < g + 1) lo = mid + 1; else hi = mid; }
    int end = lo;
    int t = threadIdx.x;
    float acc = 0.f;
    for (int i = start; i < end; ++i) acc += h[(size_t)i * 128 + t];
    float cnt = (float)(end - start);
    pooled[g * 128 + t] = acc / fmaxf(cnt, 1.0f);
}

__global__ void final_kernel(const float* __restrict__ pooled, const float* __restrict__ Wl,
                             const float* __restrict__ bl, float* __restrict__ out, int n_classes) {
    __shared__ float ps[128];
    int g = blockIdx.x;
    int t = threadIdx.x;
    ps[t]      = pooled[g * 128 + t];
    ps[t + 64] = pooled[g * 128 + 64 + t];
    __syncthreads();
    if (t < n_classes) {
        float acc = bl[t];
        for (int k = 0; k < 128; ++k)
            acc = fmaf(ps[k], Wl[k * n_classes + t], acc);
        out[g * n_classes + t] = acc;
    }
}

extern "C" void kernel_launch(void* const* d_in, const int* in_sizes, int n_in,
                              void* d_out, int out_size, void* d_ws, size_t ws_size,
                              hipStream_t stream) {
    const float* x     = (const float*)d_in[0];
    const int*   ei    = (const int*)d_in[1];
    const int*   batch = (const int*)d_in[2];
    const float* W1 = (const float*)d_in[3];
    const float* b1 = (const float*)d_in[4];
    const float* W2 = (const float*)d_in[5];
    const float* b2 = (const float*)d_in[6];
    const float* W3 = (const float*)d_in[7];
    const float* b3 = (const float*)d_in[8];
    const float* Wl = (const float*)d_in[9];
    const float* bl = (const float*)d_in[10];
    float* out = (float*)d_out;

    const int N = in_sizes[0] / 128;
    const int E = in_sizes[1] / 2;
    const int C = 10;
    const int G = out_size / C;

    const int* srcI = ei;
    const int* dstI = ei + E;

    char* w = (char*)d_ws;
    size_t off = 0;
    auto alloc = [&](size_t bytes) -> void* {
        void* p = w + off;
        off = (off + bytes + 255) & ~(size_t)255;
        return p;
    };
    const int scanBlocks = (N + 1023) / 1024;

    int*    cnt       = (int*)alloc((size_t)N * 4);
    int*    rowptr    = (int*)alloc((size_t)(N + 1) * 4);
    float*  dinv      = (float*)alloc((size_t)N * 4);
    int*    csr_src   = (int*)alloc((size_t)E * 4);
    float*  csr_w     = (float*)alloc((size_t)E * 4);
    int*    blockSums = (int*)alloc((size_t)scanBlocks * 4);
    int*    blockOff  = (int*)alloc((size_t)scanBlocks * 4);
    __half* h16       = (__half*)alloc((size_t)N * 128 * 2);
    float*  bufB      = (float*)alloc((size_t)N * 128 * 4);
    float*  pooled    = (float*)alloc((size_t)G * 128 * 4);

    // ---- CSR build (once) ----
    hipMemsetAsync(cnt, 0, (size_t)N * 4, stream);
    hist_kernel<<<(E + 255) / 256, 256, 0, stream>>>(dstI, cnt, E);
    scan1_kernel<<<scanBlocks, 256, 0, stream>>>(cnt, blockSums, N);
    scan_top_kernel<<<1, 1024, 0, stream>>>(blockSums, blockOff, rowptr + N, scanBlocks);
    scan2_kernel<<<scanBlocks, 256, 0, stream>>>(cnt, blockOff, rowptr, N);
    dinv_kernel<<<(N + 255) / 256, 256, 0, stream>>>(rowptr, dinv, N);
    hipMemcpyAsync(cnt, rowptr, (size_t)N * 4, hipMemcpyDeviceToDevice, stream);
    build_kernel<<<(E + 255) / 256, 256, 0, stream>>>(srcI, dstI, dinv, cnt, csr_src, csr_w, E);

    const int gemmBlocks = (N + 127) / 128;
    const int gathBlocks = (N * 16 + 255) / 256;

    // ---- layer 1 ----
    gemm128_kernel<<<gemmBlocks, 256, 0, stream>>>(x, W1, h16, N);
    gather_kernel<<<gathBlocks, 256, 0, stream>>>(rowptr, csr_src, csr_w, dinv, h16, b1, bufB, N, 1);
    // ---- layer 2 ----
    gemm128_kernel<<<gemmBlocks, 256, 0, stream>>>(bufB, W2, h16, N);
    gather_kernel<<<gathBlocks, 256, 0, stream>>>(rowptr, csr_src, csr_w, dinv, h16, b2, bufB, N, 1);
    // ---- layer 3 ----
    gemm128_kernel<<<gemmBlocks, 256, 0, stream>>>(bufB, W3, h16, N);
    gather_kernel<<<gathBlocks, 256, 0, stream>>>(rowptr, csr_src, csr_w, dinv, h16, b3, bufB, N, 0);

    // ---- pool + classify ----
    pool_kernel<<<G, 128, 0, stream>>>(bufB, batch, pooled, N);
    final_kernel<<<G, 64, 0, stream>>>(pooled, Wl, bl, out, C);
}

// Round 5
// 524.331 us; speedup vs baseline: 16.2115x; 1.1644x over previous
//
#include <hip/hip_runtime.h>
#include <cstdint>
#include <cstddef>

typedef _Float16 half8 __attribute__((ext_vector_type(8)));
typedef float    f32x4 __attribute__((ext_vector_type(4)));

static __device__ __forceinline__ float4 ld4(const float* p) {
    return *reinterpret_cast<const float4*>(p);
}

// load 8 halves (16B) -> 8 floats
static __device__ __forceinline__ void ld8h(const _Float16* p, float* f) {
    half8 v = *reinterpret_cast<const half8*>(p);
#pragma unroll
    for (int k = 0; k < 8; ++k) f[k] = (float)v[k];
}

// ---------- CSR build ----------

__global__ void hist_kernel(const int* __restrict__ dst, int* __restrict__ cnt, int e) {
    int i = blockIdx.x * blockDim.x + threadIdx.x;
    if (i < e) atomicAdd(&cnt[dst[i]], 1);
}

__global__ __launch_bounds__(256)
void scan1_kernel(const int* __restrict__ cnt, int* __restrict__ blockSums, int n) {
    __shared__ int ts[256];
    const int t = threadIdx.x;
    const int base = blockIdx.x * 1024 + t * 4;
    int s = 0;
    if (base + 3 < n) {
        int4 q = *reinterpret_cast<const int4*>(cnt + base);
        s = q.x + q.y + q.z + q.w;
    } else {
#pragma unroll
        for (int j = 0; j < 4; ++j) if (base + j < n) s += cnt[base + j];
    }
    ts[t] = s;
    __syncthreads();
    for (int off = 128; off > 0; off >>= 1) {
        if (t < off) ts[t] += ts[t + off];
        __syncthreads();
    }
    if (t == 0) blockSums[blockIdx.x] = ts[0];
}

__global__ __launch_bounds__(1024)
void scan_top_kernel(const int* __restrict__ blockSums, int* __restrict__ blockOff,
                     int* __restrict__ rowptr_total, int nb) {
    __shared__ int ls[1024];
    const int t = threadIdx.x;
    ls[t] = (t < nb) ? blockSums[t] : 0;
    __syncthreads();
    for (int off = 1; off < 1024; off <<= 1) {
        int v = (t >= off) ? ls[t - off] : 0;
        __syncthreads();
        ls[t] += v;
        __syncthreads();
    }
    if (t < nb) blockOff[t] = (t == 0) ? 0 : ls[t - 1];
    if (t == 1023) rowptr_total[0] = ls[1023];
}

__global__ __launch_bounds__(256)
void scan2_kernel(const int* __restrict__ cnt, const int* __restrict__ blockOff,
                  int* __restrict__ rowptr, int n) {
    __shared__ int ts[256];
    const int t = threadIdx.x;
    const int base = blockIdx.x * 1024 + t * 4;
    int v[4] = {0, 0, 0, 0};
    if (base + 3 < n) {
        int4 q = *reinterpret_cast<const int4*>(cnt + base);
        v[0] = q.x; v[1] = q.y; v[2] = q.z; v[3] = q.w;
    } else {
#pragma unroll
        for (int j = 0; j < 4; ++j) if (base + j < n) v[j] = cnt[base + j];
    }
    int s = v[0] + v[1] + v[2] + v[3];
    ts[t] = s;
    __syncthreads();
    for (int off = 1; off < 256; off <<= 1) {
        int x = (t >= off) ? ts[t - off] : 0;
        __syncthreads();
        ts[t] += x;
        __syncthreads();
    }
    int excl = blockOff[blockIdx.x] + ((t == 0) ? 0 : ts[t - 1]);
#pragma unroll
    for (int j = 0; j < 4; ++j) {
        if (base + j < n) rowptr[base + j] = excl;
        excl += v[j];
    }
}

__global__ void dinv_kernel(const int* __restrict__ rowptr, float* __restrict__ dinv, int n) {
    int i = blockIdx.x * blockDim.x + threadIdx.x;
    if (i < n) dinv[i] = rsqrtf((float)(rowptr[i + 1] - rowptr[i] + 1));
}

// bucket edges by dst; ONE packed 8B record (src, weight) per edge
__global__ void build_kernel(const int* __restrict__ src, const int* __restrict__ dst,
                             const float* __restrict__ dinv,
                             int* __restrict__ cursor, int2* __restrict__ rec, int e) {
    int i = blockIdx.x * blockDim.x + threadIdx.x;
    if (i < e) {
        int s = src[i];
        int d = dst[i];
        int pos = atomicAdd(&cursor[d], 1);
        rec[pos] = make_int2(s, __float_as_int(dinv[s] * dinv[d]));
    }
}

// ---------- MFMA GEMM: H16[N,128] = fp16( X[N,128] @ W[128,128] ) ----------
// 64 rows/block, 4 waves x 16 rows, K=128 one shot.
// A-frags direct from global; W staged transposed in LDS; C repacked via LDS scratch.
template<int IN32>
__global__ __launch_bounds__(256)
void gemm_mfma_kernel(const void* __restrict__ Xv, const float* __restrict__ W,
                      _Float16* __restrict__ H16, int n) {
    __shared__ _Float16 Wt[128][136];      // Wt[col][k]
    __shared__ _Float16 Sw[4][16][136];    // per-wave C scratch

    const int t = threadIdx.x;
    // stage W transposed (float4 global reads, scalar LDS writes)
#pragma unroll
    for (int j = 0; j < 16; ++j) {
        int i4 = t + 256 * j;              // 0..4095 float4s ; i4*4 = k*128 + c4
        int k  = i4 >> 5;
        int c4 = (i4 & 31) * 4;
        float4 v = ld4(W + (size_t)i4 * 4);
        Wt[c4 + 0][k] = (_Float16)v.x;
        Wt[c4 + 1][k] = (_Float16)v.y;
        Wt[c4 + 2][k] = (_Float16)v.z;
        Wt[c4 + 3][k] = (_Float16)v.w;
    }
    __syncthreads();

    const int wave = t >> 6;
    const int l    = t & 63;
    const int lr   = l & 15;     // row within 16x16 tile (A) / col (B, C/D)
    const int lk   = l >> 4;     // k-group (A,B) / row-group (C/D)
    const int rowA = blockIdx.x * 64 + wave * 16 + lr;

    // A fragments: k = ks*32 + lk*8 + j
    half8 a[4];
#pragma unroll
    for (int ks = 0; ks < 4; ++ks) {
#pragma unroll
        for (int j = 0; j < 8; ++j) a[ks][j] = (_Float16)0.f;
    }
    if (rowA < n) {
        if (IN32) {
            const float* X = (const float*)Xv;
#pragma unroll
            for (int ks = 0; ks < 4; ++ks) {
                const float* p = X + (size_t)rowA * 128 + ks * 32 + lk * 8;
                float4 f0 = ld4(p);
                float4 f1 = ld4(p + 4);
                a[ks][0] = (_Float16)f0.x; a[ks][1] = (_Float16)f0.y;
                a[ks][2] = (_Float16)f0.z; a[ks][3] = (_Float16)f0.w;
                a[ks][4] = (_Float16)f1.x; a[ks][5] = (_Float16)f1.y;
                a[ks][6] = (_Float16)f1.z; a[ks][7] = (_Float16)f1.w;
            }
        } else {
            const _Float16* X = (const _Float16*)Xv;
#pragma unroll
            for (int ks = 0; ks < 4; ++ks)
                a[ks] = *reinterpret_cast<const half8*>(X + (size_t)rowA * 128 + ks * 32 + lk * 8);
        }
    }

    // 8 col-tiles of 16, K=128 in 4 MFMA steps each
#pragma unroll
    for (int tt = 0; tt < 8; ++tt) {
        f32x4 acc = {0.f, 0.f, 0.f, 0.f};
#pragma unroll
        for (int ks = 0; ks < 4; ++ks) {
            half8 b = *reinterpret_cast<const half8*>(&Wt[tt * 16 + lr][ks * 32 + lk * 8]);
            acc = __builtin_amdgcn_mfma_f32_16x16x32_f16(a[ks], b, acc, 0, 0, 0);
        }
        // C/D: col = lr, row = lk*4 + r
#pragma unroll
        for (int r = 0; r < 4; ++r)
            Sw[wave][lk * 4 + r][tt * 16 + lr] = (_Float16)acc[r];
    }
    __syncthreads();

    // coalesced fp16 row writes
#pragma unroll
    for (int j = 0; j < 4; ++j) {
        int chunk = l + 64 * j;            // 0..255
        int r  = chunk >> 4;
        int c8 = chunk & 15;
        int gr = blockIdx.x * 64 + wave * 16 + r;
        if (gr < n) {
            half8 v = *reinterpret_cast<const half8*>(&Sw[wave][r][c8 * 8]);
            *reinterpret_cast<half8*>(H16 + (size_t)gr * 128 + c8 * 8) = v;
        }
    }
}

// ---------- gather (fp16 rows) + self-loop + bias (+relu), fused ----------
// 16 lanes per dst node, 8 features (16B fp16) per lane; packed edge records
template<int OUT16>
__global__ __launch_bounds__(256)
void gather_kernel(const int* __restrict__ rowptr, const int2* __restrict__ rec,
                   const float* __restrict__ dinv,
                   const _Float16* __restrict__ h16, const float* __restrict__ bias,
                   void* __restrict__ outb, int n, int do_relu) {
    int gid  = blockIdx.x * blockDim.x + threadIdx.x;
    int node = gid >> 4;
    int lane = gid & 15;
    if (node >= n) return;

    int rs = rowptr[node];
    int re = rowptr[node + 1];
    float di = dinv[node];
    const int fo = lane * 8;

    float acc[8];
    {
        float f[8];
        ld8h(h16 + (size_t)node * 128 + fo, f);
        float c = di * di;
#pragma unroll
        for (int k = 0; k < 8; ++k) acc[k] = c * f[k];
    }

    for (int e0 = rs; e0 < re; e0 += 16) {
        int m = re - e0;
        if (m > 16) m = 16;
        int   sI = 0;
        float wI = 0.f;
        if (lane < m) {
            int2 q = rec[e0 + lane];
            sI = q.x;
            wI = __int_as_float(q.y);
        }
        int j = 0;
        for (; j + 1 < m; j += 2) {
            int   s0 = __shfl(sI, j, 16);
            float w0 = __shfl(wI, j, 16);
            int   s1 = __shfl(sI, j + 1, 16);
            float w1 = __shfl(wI, j + 1, 16);
            float f0[8], f1[8];
            ld8h(h16 + (size_t)s0 * 128 + fo, f0);
            ld8h(h16 + (size_t)s1 * 128 + fo, f1);
#pragma unroll
            for (int k = 0; k < 8; ++k) {
                acc[k] = fmaf(w0, f0[k], acc[k]);
                acc[k] = fmaf(w1, f1[k], acc[k]);
            }
        }
        if (j < m) {
            int   s0 = __shfl(sI, j, 16);
            float w0 = __shfl(wI, j, 16);
            float f0[8];
            ld8h(h16 + (size_t)s0 * 128 + fo, f0);
#pragma unroll
            for (int k = 0; k < 8; ++k) acc[k] = fmaf(w0, f0[k], acc[k]);
        }
    }

    float4 b0 = ld4(bias + fo);
    float4 b1 = ld4(bias + fo + 4);
    acc[0] += b0.x; acc[1] += b0.y; acc[2] += b0.z; acc[3] += b0.w;
    acc[4] += b1.x; acc[5] += b1.y; acc[6] += b1.z; acc[7] += b1.w;
    if (do_relu) {
#pragma unroll
        for (int k = 0; k < 8; ++k) acc[k] = fmaxf(acc[k], 0.f);
    }
    if (OUT16) {
        half8 v;
#pragma unroll
        for (int k = 0; k < 8; ++k) v[k] = (_Float16)acc[k];
        *reinterpret_cast<half8*>((_Float16*)outb + (size_t)node * 128 + fo) = v;
    } else {
        float* op = (float*)outb + (size_t)node * 128 + fo;
        *reinterpret_cast<float4*>(op)     = make_float4(acc[0], acc[1], acc[2], acc[3]);
        *reinterpret_cast<float4*>(op + 4) = make_float4(acc[4], acc[5], acc[6], acc[7]);
    }
}

// ---------- pooling + classifier ----------

__global__ void pool_kernel(const _Float16* __restrict__ h, const int* __restrict__ batch,
                            float* __restrict__ pooled, int n) {
    int g = blockIdx.x;
    int lo = 0, hi = n;
    while (lo < hi) { int mid = (lo + hi) >> 1; if (batch[mid] < g) lo = mid + 1; else hi = mid; }
    int start = lo;
    hi = n;
    while (lo < hi) { int mid = (lo + hi) >> 1; if (batch[mid] < g + 1) lo = mid + 1; else hi = mid; }
    int end = lo;
    int t = threadIdx.x;
    float acc = 0.f;
    for (int i = start; i < end; ++i) acc += (float)h[(size_t)i * 128 + t];
    float cnt = (float)(end - start);
    pooled[g * 128 + t] = acc / fmaxf(cnt, 1.0f);
}

__global__ void final_kernel(const float* __restrict__ pooled, const float* __restrict__ Wl,
                             const float* __restrict__ bl, float* __restrict__ out, int n_classes) {
    __shared__ float ps[128];
    int g = blockIdx.x;
    int t = threadIdx.x;
    ps[t]      = pooled[g * 128 + t];
    ps[t + 64] = pooled[g * 128 + 64 + t];
    __syncthreads();
    if (t < n_classes) {
        float acc = bl[t];
        for (int k = 0; k < 128; ++k)
            acc = fmaf(ps[k], Wl[k * n_classes + t], acc);
        out[g * n_classes + t] = acc;
    }
}

extern "C" void kernel_launch(void* const* d_in, const int* in_sizes, int n_in,
                              void* d_out, int out_size, void* d_ws, size_t ws_size,
                              hipStream_t stream) {
    const float* x     = (const float*)d_in[0];
    const int*   ei    = (const int*)d_in[1];
    const int*   batch = (const int*)d_in[2];
    const float* W1 = (const float*)d_in[3];
    const float* b1 = (const float*)d_in[4];
    const float* W2 = (const float*)d_in[5];
    const float* b2 = (const float*)d_in[6];
    const float* W3 = (const float*)d_in[7];
    const float* b3 = (const float*)d_in[8];
    const float* Wl = (const float*)d_in[9];
    const float* bl = (const float*)d_in[10];
    float* out = (float*)d_out;

    const int N = in_sizes[0] / 128;
    const int E = in_sizes[1] / 2;
    const int C = 10;
    const int G = out_size / C;

    const int* srcI = ei;
    const int* dstI = ei + E;

    char* w = (char*)d_ws;
    size_t off = 0;
    auto alloc = [&](size_t bytes) -> void* {
        void* p = w + off;
        off = (off + bytes + 255) & ~(size_t)255;
        return p;
    };
    const int scanBlocks = (N + 1023) / 1024;

    int*      cnt       = (int*)alloc((size_t)N * 4);
    int*      rowptr    = (int*)alloc((size_t)(N + 1) * 4);
    float*    dinv      = (float*)alloc((size_t)N * 4);
    int2*     rec       = (int2*)alloc((size_t)E * 8);
    int*      blockSums = (int*)alloc((size_t)scanBlocks * 4);
    int*      blockOff  = (int*)alloc((size_t)scanBlocks * 4);
    _Float16* h16       = (_Float16*)alloc((size_t)N * 128 * 2);   // GEMM out
    _Float16* act16     = (_Float16*)alloc((size_t)N * 128 * 2);   // gather out
    float*    pooled    = (float*)alloc((size_t)G * 128 * 4);

    // ---- CSR build (once) ----
    hipMemsetAsync(cnt, 0, (size_t)N * 4, stream);
    hist_kernel<<<(E + 255) / 256, 256, 0, stream>>>(dstI, cnt, E);
    scan1_kernel<<<scanBlocks, 256, 0, stream>>>(cnt, blockSums, N);
    scan_top_kernel<<<1, 1024, 0, stream>>>(blockSums, blockOff, rowptr + N, scanBlocks);
    scan2_kernel<<<scanBlocks, 256, 0, stream>>>(cnt, blockOff, rowptr, N);
    dinv_kernel<<<(N + 255) / 256, 256, 0, stream>>>(rowptr, dinv, N);
    hipMemcpyAsync(cnt, rowptr, (size_t)N * 4, hipMemcpyDeviceToDevice, stream);
    build_kernel<<<(E + 255) / 256, 256, 0, stream>>>(srcI, dstI, dinv, cnt, rec, E);

    const int gemmBlocks = (N + 63) / 64;
    const int gathBlocks = (N * 16 + 255) / 256;

    // ---- layer 1 ----
    gemm_mfma_kernel<1><<<gemmBlocks, 256, 0, stream>>>(x, W1, h16, N);
    gather_kernel<1><<<gathBlocks, 256, 0, stream>>>(rowptr, rec, dinv, h16, b1, act16, N, 1);
    // ---- layer 2 ----
    gemm_mfma_kernel<0><<<gemmBlocks, 256, 0, stream>>>(act16, W2, h16, N);
    gather_kernel<1><<<gathBlocks, 256, 0, stream>>>(rowptr, rec, dinv, h16, b2, act16, N, 1);
    // ---- layer 3 ----
    gemm_mfma_kernel<0><<<gemmBlocks, 256, 0, stream>>>(act16, W3, h16, N);
    gather_kernel<1><<<gathBlocks, 256, 0, stream>>>(rowptr, rec, dinv, h16, b3, act16, N, 0);

    // ---- pool + classify ----
    pool_kernel<<<G, 128, 0, stream>>>(act16, batch, pooled, N);
    final_kernel<<<G, 64, 0, stream>>>(pooled, Wl, bl, out, C);
}

// Round 6
// 418.622 us; speedup vs baseline: 20.3052x; 1.2525x over previous
//
#include <hip/hip_runtime.h>
#include <cstdint>
#include <cstddef>

typedef _Float16 half8 __attribute__((ext_vector_type(8)));
typedef float    f32x4 __attribute__((ext_vector_type(4)));

#define NBLK 512        // blocks for binning passes
#define BSHIFT 8        // bucket = dst >> 8  (256 nodes per bucket)

static __device__ __forceinline__ float4 ld4(const float* p) {
    return *reinterpret_cast<const float4*>(p);
}

static __device__ __forceinline__ void ld8h(const _Float16* p, float* f) {
    half8 v = *reinterpret_cast<const half8*>(p);
#pragma unroll
    for (int k = 0; k < 8; ++k) f[k] = (float)v[k];
}

// ---------- binned CSR build ----------

// Pass A1: per-(bucket, block) counts, bucket-major layout cntM[b*NBLK + j]
__global__ __launch_bounds__(256)
void binA_count(const int* __restrict__ dst, int* __restrict__ cntM,
                int e, int nb, int tile) {
    __shared__ int lc[512];
    const int t = threadIdx.x, j = blockIdx.x;
    lc[t] = 0; lc[t + 256] = 0;
    __syncthreads();
    const int lo = j * tile;
    const int hi = min(e, lo + tile);
    for (int i = lo + t; i < hi; i += 256) atomicAdd(&lc[dst[i] >> BSHIFT], 1);
    __syncthreads();
    for (int b = t; b < nb; b += 256) cntM[b * NBLK + j] = lc[b];
}

// generic hierarchical exclusive scan (3 kernels)
__global__ __launch_bounds__(256)
void scan1_kernel(const int* __restrict__ cnt, int* __restrict__ blockSums, int n) {
    __shared__ int ts[256];
    const int t = threadIdx.x;
    const int base = blockIdx.x * 1024 + t * 4;
    int s = 0;
    if (base + 3 < n) {
        int4 q = *reinterpret_cast<const int4*>(cnt + base);
        s = q.x + q.y + q.z + q.w;
    } else {
#pragma unroll
        for (int j = 0; j < 4; ++j) if (base + j < n) s += cnt[base + j];
    }
    ts[t] = s;
    __syncthreads();
    for (int off = 128; off > 0; off >>= 1) {
        if (t < off) ts[t] += ts[t + off];
        __syncthreads();
    }
    if (t == 0) blockSums[blockIdx.x] = ts[0];
}

__global__ __launch_bounds__(1024)
void scan_top_kernel(const int* __restrict__ blockSums, int* __restrict__ blockOff,
                     int* __restrict__ total, int nb) {
    __shared__ int ls[1024];
    const int t = threadIdx.x;
    ls[t] = (t < nb) ? blockSums[t] : 0;
    __syncthreads();
    for (int off = 1; off < 1024; off <<= 1) {
        int v = (t >= off) ? ls[t - off] : 0;
        __syncthreads();
        ls[t] += v;
        __syncthreads();
    }
    if (t < nb) blockOff[t] = (t == 0) ? 0 : ls[t - 1];
    if (t == 1023) total[0] = ls[1023];
}

__global__ __launch_bounds__(256)
void scan2_kernel(const int* __restrict__ cnt, const int* __restrict__ blockOff,
                  int* __restrict__ outp, int n) {
    __shared__ int ts[256];
    const int t = threadIdx.x;
    const int base = blockIdx.x * 1024 + t * 4;
    int v[4] = {0, 0, 0, 0};
    if (base + 3 < n) {
        int4 q = *reinterpret_cast<const int4*>(cnt + base);
        v[0] = q.x; v[1] = q.y; v[2] = q.z; v[3] = q.w;
    } else {
#pragma unroll
        for (int j = 0; j < 4; ++j) if (base + j < n) v[j] = cnt[base + j];
    }
    int s = v[0] + v[1] + v[2] + v[3];
    ts[t] = s;
    __syncthreads();
    for (int off = 1; off < 256; off <<= 1) {
        int x = (t >= off) ? ts[t - off] : 0;
        __syncthreads();
        ts[t] += x;
        __syncthreads();
    }
    int excl = blockOff[blockIdx.x] + ((t == 0) ? 0 : ts[t - 1]);
#pragma unroll
    for (int j = 0; j < 4; ++j) {
        if (base + j < n) outp[base + j] = excl;
        excl += v[j];
    }
}

// Pass A2: place (src,dst) into bucket-grouped staging at scanned offsets (no global atomics)
__global__ __launch_bounds__(256)
void binA_place(const int* __restrict__ src, const int* __restrict__ dst,
                const int* __restrict__ offM, int2* __restrict__ staging,
                int e, int nb, int tile) {
    __shared__ int cur[512];
    const int t = threadIdx.x, j = blockIdx.x;
    for (int b = t; b < nb; b += 256) cur[b] = offM[b * NBLK + j];
    __syncthreads();
    const int lo = j * tile;
    const int hi = min(e, lo + tile);
    for (int i = lo + t; i < hi; i += 256) {
        int s = src[i];
        int d = dst[i];
        int pos = atomicAdd(&cur[d >> BSHIFT], 1);
        staging[pos] = make_int2(s, d);
    }
}

// Phase B1: one block per bucket — local hist + scan -> rowptr, dinv
__global__ __launch_bounds__(256)
void bucket_rows(const int2* __restrict__ staging, const int* __restrict__ offM,
                 int* __restrict__ rowptr, float* __restrict__ dinv,
                 int n, int nb, int e) {
    __shared__ int lc[256];
    __shared__ int ls[256];
    const int b = blockIdx.x, t = threadIdx.x;
    const int base = offM[b * NBLK];
    const int end  = (b + 1 < nb) ? offM[(b + 1) * NBLK] : e;
    const int d0 = b << BSHIFT;
    const int R  = min(n - d0, 256);
    lc[t] = 0;
    __syncthreads();
    for (int i = base + t; i < end; i += 256) atomicAdd(&lc[staging[i].y - d0], 1);
    __syncthreads();
    const int deg = lc[t];
    ls[t] = deg;
    __syncthreads();
    for (int off = 1; off < 256; off <<= 1) {
        int v = (t >= off) ? ls[t - off] : 0;
        __syncthreads();
        ls[t] += v;
        __syncthreads();
    }
    int excl = (t == 0) ? 0 : ls[t - 1];
    if (t < R) {
        rowptr[d0 + t] = base + excl;
        dinv[d0 + t]   = rsqrtf((float)(deg + 1));
    }
    if (b == nb - 1 && t == 0) rowptr[n] = e;
}

// Phase B2: one block per bucket — scatter (src, w) into private CSR region
__global__ __launch_bounds__(256)
void bucket_scatter(const int2* __restrict__ staging, const int* __restrict__ offM,
                    const int* __restrict__ rowptr, const float* __restrict__ dinv,
                    int2* __restrict__ rec, int n, int nb, int e) {
    __shared__ int   cur[256];
    __shared__ float ldv[256];
    const int b = blockIdx.x, t = threadIdx.x;
    const int base = offM[b * NBLK];
    const int end  = (b + 1 < nb) ? offM[(b + 1) * NBLK] : e;
    const int d0 = b << BSHIFT;
    const int R  = min(n - d0, 256);
    if (t < R) {
        cur[t] = rowptr[d0 + t];
        ldv[t] = dinv[d0 + t];
    }
    __syncthreads();
    for (int i = base + t; i < end; i += 256) {
        int2 q = staging[i];
        int dl = q.y - d0;
        int pos = atomicAdd(&cur[dl], 1);
        float w = dinv[q.x] * ldv[dl];
        rec[pos] = make_int2(q.x, __float_as_int(w));
    }
}

// ---------- MFMA GEMM: H16[N,128] = fp16( X[N,128] @ W[128,128] ) ----------
template<int IN32>
__global__ __launch_bounds__(256)
void gemm_mfma_kernel(const void* __restrict__ Xv, const float* __restrict__ W,
                      _Float16* __restrict__ H16, int n) {
    __shared__ _Float16 Wt[128][136];
    __shared__ _Float16 Sw[4][16][136];

    const int t = threadIdx.x;
#pragma unroll
    for (int j = 0; j < 16; ++j) {
        int i4 = t + 256 * j;
        int k  = i4 >> 5;
        int c4 = (i4 & 31) * 4;
        float4 v = ld4(W + (size_t)i4 * 4);
        Wt[c4 + 0][k] = (_Float16)v.x;
        Wt[c4 + 1][k] = (_Float16)v.y;
        Wt[c4 + 2][k] = (_Float16)v.z;
        Wt[c4 + 3][k] = (_Float16)v.w;
    }
    __syncthreads();

    const int wave = t >> 6;
    const int l    = t & 63;
    const int lr   = l & 15;
    const int lk   = l >> 4;
    const int rowA = blockIdx.x * 64 + wave * 16 + lr;

    half8 a[4];
#pragma unroll
    for (int ks = 0; ks < 4; ++ks) {
#pragma unroll
        for (int j = 0; j < 8; ++j) a[ks][j] = (_Float16)0.f;
    }
    if (rowA < n) {
        if (IN32) {
            const float* X = (const float*)Xv;
#pragma unroll
            for (int ks = 0; ks < 4; ++ks) {
                const float* p = X + (size_t)rowA * 128 + ks * 32 + lk * 8;
                float4 f0 = ld4(p);
                float4 f1 = ld4(p + 4);
                a[ks][0] = (_Float16)f0.x; a[ks][1] = (_Float16)f0.y;
                a[ks][2] = (_Float16)f0.z; a[ks][3] = (_Float16)f0.w;
                a[ks][4] = (_Float16)f1.x; a[ks][5] = (_Float16)f1.y;
                a[ks][6] = (_Float16)f1.z; a[ks][7] = (_Float16)f1.w;
            }
        } else {
            const _Float16* X = (const _Float16*)Xv;
#pragma unroll
            for (int ks = 0; ks < 4; ++ks)
                a[ks] = *reinterpret_cast<const half8*>(X + (size_t)rowA * 128 + ks * 32 + lk * 8);
        }
    }

#pragma unroll
    for (int tt = 0; tt < 8; ++tt) {
        f32x4 acc = {0.f, 0.f, 0.f, 0.f};
#pragma unroll
        for (int ks = 0; ks < 4; ++ks) {
            half8 b = *reinterpret_cast<const half8*>(&Wt[tt * 16 + lr][ks * 32 + lk * 8]);
            acc = __builtin_amdgcn_mfma_f32_16x16x32_f16(a[ks], b, acc, 0, 0, 0);
        }
#pragma unroll
        for (int r = 0; r < 4; ++r)
            Sw[wave][lk * 4 + r][tt * 16 + lr] = (_Float16)acc[r];
    }
    __syncthreads();

#pragma unroll
    for (int j = 0; j < 4; ++j) {
        int chunk = l + 64 * j;
        int r  = chunk >> 4;
        int c8 = chunk & 15;
        int gr = blockIdx.x * 64 + wave * 16 + r;
        if (gr < n) {
            half8 v = *reinterpret_cast<const half8*>(&Sw[wave][r][c8 * 8]);
            *reinterpret_cast<half8*>(H16 + (size_t)gr * 128 + c8 * 8) = v;
        }
    }
}

// ---------- gather (fp16 rows) + self-loop + bias (+relu), fused ----------
template<int OUT16>
__global__ __launch_bounds__(256)
void gather_kernel(const int* __restrict__ rowptr, const int2* __restrict__ rec,
                   const float* __restrict__ dinv,
                   const _Float16* __restrict__ h16, const float* __restrict__ bias,
                   void* __restrict__ outb, int n, int do_relu) {
    int gid  = blockIdx.x * blockDim.x + threadIdx.x;
    int node = gid >> 4;
    int lane = gid & 15;
    if (node >= n) return;

    int rs = rowptr[node];
    int re = rowptr[node + 1];
    float di = dinv[node];
    const int fo = lane * 8;

    float acc[8];
    {
        float f[8];
        ld8h(h16 + (size_t)node * 128 + fo, f);
        float c = di * di;
#pragma unroll
        for (int k = 0; k < 8; ++k) acc[k] = c * f[k];
    }

    for (int e0 = rs; e0 < re; e0 += 16) {
        int m = re - e0;
        if (m > 16) m = 16;
        int   sI = 0;
        float wI = 0.f;
        if (lane < m) {
            int2 q = rec[e0 + lane];
            sI = q.x;
            wI = __int_as_float(q.y);
        }
        int j = 0;
        for (; j + 1 < m; j += 2) {
            int   s0 = __shfl(sI, j, 16);
            float w0 = __shfl(wI, j, 16);
            int   s1 = __shfl(sI, j + 1, 16);
            float w1 = __shfl(wI, j + 1, 16);
            float f0[8], f1[8];
            ld8h(h16 + (size_t)s0 * 128 + fo, f0);
            ld8h(h16 + (size_t)s1 * 128 + fo, f1);
#pragma unroll
            for (int k = 0; k < 8; ++k) {
                acc[k] = fmaf(w0, f0[k], acc[k]);
                acc[k] = fmaf(w1, f1[k], acc[k]);
            }
        }
        if (j < m) {
            int   s0 = __shfl(sI, j, 16);
            float w0 = __shfl(wI, j, 16);
            float f0[8];
            ld8h(h16 + (size_t)s0 * 128 + fo, f0);
#pragma unroll
            for (int k = 0; k < 8; ++k) acc[k] = fmaf(w0, f0[k], acc[k]);
        }
    }

    float4 b0 = ld4(bias + fo);
    float4 b1 = ld4(bias + fo + 4);
    acc[0] += b0.x; acc[1] += b0.y; acc[2] += b0.z; acc[3] += b0.w;
    acc[4] += b1.x; acc[5] += b1.y; acc[6] += b1.z; acc[7] += b1.w;
    if (do_relu) {
#pragma unroll
        for (int k = 0; k < 8; ++k) acc[k] = fmaxf(acc[k], 0.f);
    }
    if (OUT16) {
        half8 v;
#pragma unroll
        for (int k = 0; k < 8; ++k) v[k] = (_Float16)acc[k];
        *reinterpret_cast<half8*>((_Float16*)outb + (size_t)node * 128 + fo) = v;
    } else {
        float* op = (float*)outb + (size_t)node * 128 + fo;
        *reinterpret_cast<float4*>(op)     = make_float4(acc[0], acc[1], acc[2], acc[3]);
        *reinterpret_cast<float4*>(op + 4) = make_float4(acc[4], acc[5], acc[6], acc[7]);
    }
}

// ---------- pooling + classifier ----------

__global__ void pool_kernel(const _Float16* __restrict__ h, const int* __restrict__ batch,
                            float* __restrict__ pooled, int n) {
    int g = blockIdx.x;
    int lo = 0, hi = n;
    while (lo < hi) { int mid = (lo + hi) >> 1; if (batch[mid] < g) lo = mid + 1; else hi = mid; }
    int start = lo;
    hi = n;
    while (lo < hi) { int mid = (lo + hi) >> 1; if (batch[mid] < g + 1) lo = mid + 1; else hi = mid; }
    int end = lo;
    int t = threadIdx.x;
    float acc = 0.f;
    for (int i = start; i < end; ++i) acc += (float)h[(size_t)i * 128 + t];
    float cnt = (float)(end - start);
    pooled[g * 128 + t] = acc / fmaxf(cnt, 1.0f);
}

__global__ void final_kernel(const float* __restrict__ pooled, const float* __restrict__ Wl,
                             const float* __restrict__ bl, float* __restrict__ out, int n_classes) {
    __shared__ float ps[128];
    int g = blockIdx.x;
    int t = threadIdx.x;
    ps[t]      = pooled[g * 128 + t];
    ps[t + 64] = pooled[g * 128 + 64 + t];
    __syncthreads();
    if (t < n_classes) {
        float acc = bl[t];
        for (int k = 0; k < 128; ++k)
            acc = fmaf(ps[k], Wl[k * n_classes + t], acc);
        out[g * n_classes + t] = acc;
    }
}

extern "C" void kernel_launch(void* const* d_in, const int* in_sizes, int n_in,
                              void* d_out, int out_size, void* d_ws, size_t ws_size,
                              hipStream_t stream) {
    const float* x     = (const float*)d_in[0];
    const int*   ei    = (const int*)d_in[1];
    const int*   batch = (const int*)d_in[2];
    const float* W1 = (const float*)d_in[3];
    const float* b1 = (const float*)d_in[4];
    const float* W2 = (const float*)d_in[5];
    const float* b2 = (const float*)d_in[6];
    const float* W3 = (const float*)d_in[7];
    const float* b3 = (const float*)d_in[8];
    const float* Wl = (const float*)d_in[9];
    const float* bl = (const float*)d_in[10];
    float* out = (float*)d_out;

    const int N = in_sizes[0] / 128;
    const int E = in_sizes[1] / 2;
    const int C = 10;
    const int G = out_size / C;

    const int* srcI = ei;
    const int* dstI = ei + E;

    const int NB   = (N + 255) >> BSHIFT;      // buckets
    const int M    = NB * NBLK;                // count-matrix size
    const int TILE = (E + NBLK - 1) / NBLK;
    const int scanB = (M + 1023) / 1024;

    char* w = (char*)d_ws;
    size_t off = 0;
    auto alloc = [&](size_t bytes) -> void* {
        void* p = w + off;
        off = (off + bytes + 255) & ~(size_t)255;
        return p;
    };

    int*      rowptr    = (int*)alloc((size_t)(N + 1) * 4);
    float*    dinv      = (float*)alloc((size_t)N * 4);
    int2*     rec       = (int2*)alloc((size_t)E * 8);
    int2*     staging   = (int2*)alloc((size_t)E * 8);
    int*      cntM      = (int*)alloc((size_t)M * 4);
    int*      offM      = (int*)alloc((size_t)M * 4);
    int*      blockSums = (int*)alloc((size_t)scanB * 4);
    int*      blockOff  = (int*)alloc((size_t)scanB * 4);
    int*      scrTotal  = (int*)alloc(256);
    _Float16* h16       = (_Float16*)alloc((size_t)N * 128 * 2);
    _Float16* act16     = (_Float16*)alloc((size_t)N * 128 * 2);
    float*    pooled    = (float*)alloc((size_t)G * 128 * 4);

    // ---- binned CSR build (once) ----
    binA_count<<<NBLK, 256, 0, stream>>>(dstI, cntM, E, NB, TILE);
    scan1_kernel<<<scanB, 256, 0, stream>>>(cntM, blockSums, M);
    scan_top_kernel<<<1, 1024, 0, stream>>>(blockSums, blockOff, scrTotal, scanB);
    scan2_kernel<<<scanB, 256, 0, stream>>>(cntM, blockOff, offM, M);
    binA_place<<<NBLK, 256, 0, stream>>>(srcI, dstI, offM, staging, E, NB, TILE);
    bucket_rows<<<NB, 256, 0, stream>>>(staging, offM, rowptr, dinv, N, NB, E);
    bucket_scatter<<<NB, 256, 0, stream>>>(staging, offM, rowptr, dinv, rec, N, NB, E);

    const int gemmBlocks = (N + 63) / 64;
    const int gathBlocks = (N * 16 + 255) / 256;

    // ---- layer 1 ----
    gemm_mfma_kernel<1><<<gemmBlocks, 256, 0, stream>>>(x, W1, h16, N);
    gather_kernel<1><<<gathBlocks, 256, 0, stream>>>(rowptr, rec, dinv, h16, b1, act16, N, 1);
    // ---- layer 2 ----
    gemm_mfma_kernel<0><<<gemmBlocks, 256, 0, stream>>>(act16, W2, h16, N);
    gather_kernel<1><<<gathBlocks, 256, 0, stream>>>(rowptr, rec, dinv, h16, b2, act16, N, 1);
    // ---- layer 3 ----
    gemm_mfma_kernel<0><<<gemmBlocks, 256, 0, stream>>>(act16, W3, h16, N);
    gather_kernel<1><<<gathBlocks, 256, 0, stream>>>(rowptr, rec, dinv, h16, b3, act16, N, 0);

    // ---- pool + classify ----
    pool_kernel<<<G, 128, 0, stream>>>(act16, batch, pooled, N);
    final_kernel<<<G, 64, 0, stream>>>(pooled, Wl, bl, out, C);
}

// Round 7
// 361.745 us; speedup vs baseline: 23.4978x; 1.1572x over previous
//
#include <hip/hip_runtime.h>
#include <cstdint>
#include <cstddef>

typedef _Float16 half8 __attribute__((ext_vector_type(8)));
typedef float    f32x4 __attribute__((ext_vector_type(4)));

#define NBLK 512        // blocks for binning passes
#define BSHIFT 8        // bucket = dst >> 8  (256 nodes per bucket)

static __device__ __forceinline__ float4 ld4(const float* p) {
    return *reinterpret_cast<const float4*>(p);
}

static __device__ __forceinline__ void ld8h(const _Float16* p, float* f) {
    half8 v = *reinterpret_cast<const half8*>(p);
#pragma unroll
    for (int k = 0; k < 8; ++k) f[k] = (float)v[k];
}

// ---------- binned CSR build ----------

// Pass A1: per-(bucket, block) counts, bucket-major layout cntM[b*NBLK + j]
__global__ __launch_bounds__(256)
void binA_count(const int* __restrict__ dst, int* __restrict__ cntM,
                int e, int nb, int tile) {
    __shared__ int lc[512];
    const int t = threadIdx.x, j = blockIdx.x;
    lc[t] = 0; lc[t + 256] = 0;
    __syncthreads();
    const int lo = j * tile;
    const int hi = min(e, lo + tile);
    for (int i = lo + t; i < hi; i += 256) atomicAdd(&lc[dst[i] >> BSHIFT], 1);
    __syncthreads();
    for (int b = t; b < nb; b += 256) cntM[b * NBLK + j] = lc[b];
}

// generic hierarchical exclusive scan (3 kernels)
__global__ __launch_bounds__(256)
void scan1_kernel(const int* __restrict__ cnt, int* __restrict__ blockSums, int n) {
    __shared__ int ts[256];
    const int t = threadIdx.x;
    const int base = blockIdx.x * 1024 + t * 4;
    int s = 0;
    if (base + 3 < n) {
        int4 q = *reinterpret_cast<const int4*>(cnt + base);
        s = q.x + q.y + q.z + q.w;
    } else {
#pragma unroll
        for (int j = 0; j < 4; ++j) if (base + j < n) s += cnt[base + j];
    }
    ts[t] = s;
    __syncthreads();
    for (int off = 128; off > 0; off >>= 1) {
        if (t < off) ts[t] += ts[t + off];
        __syncthreads();
    }
    if (t == 0) blockSums[blockIdx.x] = ts[0];
}

__global__ __launch_bounds__(1024)
void scan_top_kernel(const int* __restrict__ blockSums, int* __restrict__ blockOff,
                     int* __restrict__ total, int nb) {
    __shared__ int ls[1024];
    const int t = threadIdx.x;
    ls[t] = (t < nb) ? blockSums[t] : 0;
    __syncthreads();
    for (int off = 1; off < 1024; off <<= 1) {
        int v = (t >= off) ? ls[t - off] : 0;
        __syncthreads();
        ls[t] += v;
        __syncthreads();
    }
    if (t < nb) blockOff[t] = (t == 0) ? 0 : ls[t - 1];
    if (t == 1023) total[0] = ls[1023];
}

__global__ __launch_bounds__(256)
void scan2_kernel(const int* __restrict__ cnt, const int* __restrict__ blockOff,
                  int* __restrict__ outp, int n) {
    __shared__ int ts[256];
    const int t = threadIdx.x;
    const int base = blockIdx.x * 1024 + t * 4;
    int v[4] = {0, 0, 0, 0};
    if (base + 3 < n) {
        int4 q = *reinterpret_cast<const int4*>(cnt + base);
        v[0] = q.x; v[1] = q.y; v[2] = q.z; v[3] = q.w;
    } else {
#pragma unroll
        for (int j = 0; j < 4; ++j) if (base + j < n) v[j] = cnt[base + j];
    }
    int s = v[0] + v[1] + v[2] + v[3];
    ts[t] = s;
    __syncthreads();
    for (int off = 1; off < 256; off <<= 1) {
        int x = (t >= off) ? ts[t - off] : 0;
        __syncthreads();
        ts[t] += x;
        __syncthreads();
    }
    int excl = blockOff[blockIdx.x] + ((t == 0) ? 0 : ts[t - 1]);
#pragma unroll
    for (int j = 0; j < 4; ++j) {
        if (base + j < n) outp[base + j] = excl;
        excl += v[j];
    }
}

// Pass A2: place (src,dst) into bucket-grouped staging at scanned offsets (no global atomics)
__global__ __launch_bounds__(256)
void binA_place(const int* __restrict__ src, const int* __restrict__ dst,
                const int* __restrict__ offM, int2* __restrict__ staging,
                int e, int nb, int tile) {
    __shared__ int cur[512];
    const int t = threadIdx.x, j = blockIdx.x;
    for (int b = t; b < nb; b += 256) cur[b] = offM[b * NBLK + j];
    __syncthreads();
    const int lo = j * tile;
    const int hi = min(e, lo + tile);
    for (int i = lo + t; i < hi; i += 256) {
        int s = src[i];
        int d = dst[i];
        int pos = atomicAdd(&cur[d >> BSHIFT], 1);
        staging[pos] = make_int2(s, d);
    }
}

// Phase B1: one block per bucket — local hist + scan -> rowptr, dinv
__global__ __launch_bounds__(256)
void bucket_rows(const int2* __restrict__ staging, const int* __restrict__ offM,
                 int* __restrict__ rowptr, float* __restrict__ dinv,
                 int n, int nb, int e) {
    __shared__ int lc[256];
    __shared__ int ls[256];
    const int b = blockIdx.x, t = threadIdx.x;
    const int base = offM[b * NBLK];
    const int end  = (b + 1 < nb) ? offM[(b + 1) * NBLK] : e;
    const int d0 = b << BSHIFT;
    const int R  = min(n - d0, 256);
    lc[t] = 0;
    __syncthreads();
    for (int i = base + t; i < end; i += 256) atomicAdd(&lc[staging[i].y - d0], 1);
    __syncthreads();
    const int deg = lc[t];
    ls[t] = deg;
    __syncthreads();
    for (int off = 1; off < 256; off <<= 1) {
        int v = (t >= off) ? ls[t - off] : 0;
        __syncthreads();
        ls[t] += v;
        __syncthreads();
    }
    int excl = (t == 0) ? 0 : ls[t - 1];
    if (t < R) {
        rowptr[d0 + t] = base + excl;
        dinv[d0 + t]   = rsqrtf((float)(deg + 1));
    }
    if (b == nb - 1 && t == 0) rowptr[n] = e;
}

// Phase B2: one block per bucket — scatter (src, w) into private CSR region
__global__ __launch_bounds__(256)
void bucket_scatter(const int2* __restrict__ staging, const int* __restrict__ offM,
                    const int* __restrict__ rowptr, const float* __restrict__ dinv,
                    int2* __restrict__ rec, int n, int nb, int e) {
    __shared__ int   cur[256];
    __shared__ float ldv[256];
    const int b = blockIdx.x, t = threadIdx.x;
    const int base = offM[b * NBLK];
    const int end  = (b + 1 < nb) ? offM[(b + 1) * NBLK] : e;
    const int d0 = b << BSHIFT;
    const int R  = min(n - d0, 256);
    if (t < R) {
        cur[t] = rowptr[d0 + t];
        ldv[t] = dinv[d0 + t];
    }
    __syncthreads();
    for (int i = base + t; i < end; i += 256) {
        int2 q = staging[i];
        int dl = q.y - d0;
        int pos = atomicAdd(&cur[dl], 1);
        float w = dinv[q.x] * ldv[dl];
        rec[pos] = make_int2(q.x, __float_as_int(w));
    }
}

// ---------- MFMA GEMM: H16[N,128] = fp16( X[N,128] @ W[128,128] ) ----------
template<int IN32>
__global__ __launch_bounds__(256)
void gemm_mfma_kernel(const void* __restrict__ Xv, const float* __restrict__ W,
                      _Float16* __restrict__ H16, int n) {
    __shared__ _Float16 Wt[128][136];
    __shared__ _Float16 Sw[4][16][136];

    const int t = threadIdx.x;
#pragma unroll
    for (int j = 0; j < 16; ++j) {
        int i4 = t + 256 * j;
        int k  = i4 >> 5;
        int c4 = (i4 & 31) * 4;
        float4 v = ld4(W + (size_t)i4 * 4);
        Wt[c4 + 0][k] = (_Float16)v.x;
        Wt[c4 + 1][k] = (_Float16)v.y;
        Wt[c4 + 2][k] = (_Float16)v.z;
        Wt[c4 + 3][k] = (_Float16)v.w;
    }
    __syncthreads();

    const int wave = t >> 6;
    const int l    = t & 63;
    const int lr   = l & 15;
    const int lk   = l >> 4;
    const int rowA = blockIdx.x * 64 + wave * 16 + lr;

    half8 a[4];
#pragma unroll
    for (int ks = 0; ks < 4; ++ks) {
#pragma unroll
        for (int j = 0; j < 8; ++j) a[ks][j] = (_Float16)0.f;
    }
    if (rowA < n) {
        if (IN32) {
            const float* X = (const float*)Xv;
#pragma unroll
            for (int ks = 0; ks < 4; ++ks) {
                const float* p = X + (size_t)rowA * 128 + ks * 32 + lk * 8;
                float4 f0 = ld4(p);
                float4 f1 = ld4(p + 4);
                a[ks][0] = (_Float16)f0.x; a[ks][1] = (_Float16)f0.y;
                a[ks][2] = (_Float16)f0.z; a[ks][3] = (_Float16)f0.w;
                a[ks][4] = (_Float16)f1.x; a[ks][5] = (_Float16)f1.y;
                a[ks][6] = (_Float16)f1.z; a[ks][7] = (_Float16)f1.w;
            }
        } else {
            const _Float16* X = (const _Float16*)Xv;
#pragma unroll
            for (int ks = 0; ks < 4; ++ks)
                a[ks] = *reinterpret_cast<const half8*>(X + (size_t)rowA * 128 + ks * 32 + lk * 8);
        }
    }

#pragma unroll
    for (int tt = 0; tt < 8; ++tt) {
        f32x4 acc = {0.f, 0.f, 0.f, 0.f};
#pragma unroll
        for (int ks = 0; ks < 4; ++ks) {
            half8 b = *reinterpret_cast<const half8*>(&Wt[tt * 16 + lr][ks * 32 + lk * 8]);
            acc = __builtin_amdgcn_mfma_f32_16x16x32_f16(a[ks], b, acc, 0, 0, 0);
        }
#pragma unroll
        for (int r = 0; r < 4; ++r)
            Sw[wave][lk * 4 + r][tt * 16 + lr] = (_Float16)acc[r];
    }
    __syncthreads();

#pragma unroll
    for (int j = 0; j < 4; ++j) {
        int chunk = l + 64 * j;
        int r  = chunk >> 4;
        int c8 = chunk & 15;
        int gr = blockIdx.x * 64 + wave * 16 + r;
        if (gr < n) {
            half8 v = *reinterpret_cast<const half8*>(&Sw[wave][r][c8 * 8]);
            *reinterpret_cast<half8*>(H16 + (size_t)gr * 128 + c8 * 8) = v;
        }
    }
}

// ---------- gather (fp16 rows) + self-loop + bias (+relu), fused ----------
template<int OUT16>
__global__ __launch_bounds__(256)
void gather_kernel(const int* __restrict__ rowptr, const int2* __restrict__ rec,
                   const float* __restrict__ dinv,
                   const _Float16* __restrict__ h16, const float* __restrict__ bias,
                   void* __restrict__ outb, int n, int do_relu) {
    int gid  = blockIdx.x * blockDim.x + threadIdx.x;
    int node = gid >> 4;
    int lane = gid & 15;
    if (node >= n) return;

    int rs = rowptr[node];
    int re = rowptr[node + 1];
    float di = dinv[node];
    const int fo = lane * 8;

    float acc[8];
    {
        float f[8];
        ld8h(h16 + (size_t)node * 128 + fo, f);
        float c = di * di;
#pragma unroll
        for (int k = 0; k < 8; ++k) acc[k] = c * f[k];
    }

    for (int e0 = rs; e0 < re; e0 += 16) {
        int m = re - e0;
        if (m > 16) m = 16;
        int   sI = 0;
        float wI = 0.f;
        if (lane < m) {
            int2 q = rec[e0 + lane];
            sI = q.x;
            wI = __int_as_float(q.y);
        }
        int j = 0;
        for (; j + 1 < m; j += 2) {
            int   s0 = __shfl(sI, j, 16);
            float w0 = __shfl(wI, j, 16);
            int   s1 = __shfl(sI, j + 1, 16);
            float w1 = __shfl(wI, j + 1, 16);
            float f0[8], f1[8];
            ld8h(h16 + (size_t)s0 * 128 + fo, f0);
            ld8h(h16 + (size_t)s1 * 128 + fo, f1);
#pragma unroll
            for (int k = 0; k < 8; ++k) {
                acc[k] = fmaf(w0, f0[k], acc[k]);
                acc[k] = fmaf(w1, f1[k], acc[k]);
            }
        }
        if (j < m) {
            int   s0 = __shfl(sI, j, 16);
            float w0 = __shfl(wI, j, 16);
            float f0[8];
            ld8h(h16 + (size_t)s0 * 128 + fo, f0);
#pragma unroll
            for (int k = 0; k < 8; ++k) acc[k] = fmaf(w0, f0[k], acc[k]);
        }
    }

    float4 b0 = ld4(bias + fo);
    float4 b1 = ld4(bias + fo + 4);
    acc[0] += b0.x; acc[1] += b0.y; acc[2] += b0.z; acc[3] += b0.w;
    acc[4] += b1.x; acc[5] += b1.y; acc[6] += b1.z; acc[7] += b1.w;
    if (do_relu) {
#pragma unroll
        for (int k = 0; k < 8; ++k) acc[k] = fmaxf(acc[k], 0.f);
    }
    if (OUT16) {
        half8 v;
#pragma unroll
        for (int k = 0; k < 8; ++k) v[k] = (_Float16)acc[k];
        *reinterpret_cast<half8*>((_Float16*)outb + (size_t)node * 128 + fo) = v;
    } else {
        float* op = (float*)outb + (size_t)node * 128 + fo;
        *reinterpret_cast<float4*>(op)     = make_float4(acc[0], acc[1], acc[2], acc[3]);
        *reinterpret_cast<float4*>(op + 4) = make_float4(acc[4], acc[5], acc[6], acc[7]);
    }
}

// ---------- pooling + classifier ----------
// one block per graph: 16 row-groups x 16 lanes, half8 loads, LDS float4 tree-reduce
__global__ __launch_bounds__(256)
void pool_kernel(const _Float16* __restrict__ h, const int* __restrict__ batch,
                 float* __restrict__ pooled, int n) {
    __shared__ f32x4 red[16][34];   // 16 groups x 32 float4 (128 floats), padded
    int g = blockIdx.x;
    int lo = 0, hi = n;
    while (lo < hi) { int mid = (lo + hi) >> 1; if (batch[mid] < g) lo = mid + 1; else hi = mid; }
    int start = lo;
    hi = n;
    while (lo < hi) { int mid = (lo + hi) >> 1; if (batch[mid] < g + 1) lo = mid + 1; else hi = mid; }
    int end = lo;

    const int t   = threadIdx.x;
    const int grp = t >> 4;
    const int ln  = t & 15;

    float acc[8] = {0.f, 0.f, 0.f, 0.f, 0.f, 0.f, 0.f, 0.f};
    for (int i = start + grp; i < end; i += 16) {
        float f[8];
        ld8h(h + (size_t)i * 128 + ln * 8, f);
#pragma unroll
        for (int k = 0; k < 8; ++k) acc[k] += f[k];
    }
    red[grp][ln * 2]     = (f32x4){acc[0], acc[1], acc[2], acc[3]};
    red[grp][ln * 2 + 1] = (f32x4){acc[4], acc[5], acc[6], acc[7]};
    __syncthreads();
#pragma unroll
    for (int off = 8; off > 0; off >>= 1) {
        if (grp < off) {
            red[grp][ln * 2]     += red[grp + off][ln * 2];
            red[grp][ln * 2 + 1] += red[grp + off][ln * 2 + 1];
        }
        __syncthreads();
    }
    if (t < 128) {
        float cnt = (float)(end - start);
        pooled[g * 128 + t] = red[0][t >> 2][t & 3] / fmaxf(cnt, 1.0f);
    }
}

__global__ void final_kernel(const float* __restrict__ pooled, const float* __restrict__ Wl,
                             const float* __restrict__ bl, float* __restrict__ out, int n_classes) {
    __shared__ float ps[128];
    int g = blockIdx.x;
    int t = threadIdx.x;
    ps[t]      = pooled[g * 128 + t];
    ps[t + 64] = pooled[g * 128 + 64 + t];
    __syncthreads();
    if (t < n_classes) {
        float acc = bl[t];
        for (int k = 0; k < 128; ++k)
            acc = fmaf(ps[k], Wl[k * n_classes + t], acc);
        out[g * n_classes + t] = acc;
    }
}

extern "C" void kernel_launch(void* const* d_in, const int* in_sizes, int n_in,
                              void* d_out, int out_size, void* d_ws, size_t ws_size,
                              hipStream_t stream) {
    const float* x     = (const float*)d_in[0];
    const int*   ei    = (const int*)d_in[1];
    const int*   batch = (const int*)d_in[2];
    const float* W1 = (const float*)d_in[3];
    const float* b1 = (const float*)d_in[4];
    const float* W2 = (const float*)d_in[5];
    const float* b2 = (const float*)d_in[6];
    const float* W3 = (const float*)d_in[7];
    const float* b3 = (const float*)d_in[8];
    const float* Wl = (const float*)d_in[9];
    const float* bl = (const float*)d_in[10];
    float* out = (float*)d_out;

    const int N = in_sizes[0] / 128;
    const int E = in_sizes[1] / 2;
    const int C = 10;
    const int G = out_size / C;

    const int* srcI = ei;
    const int* dstI = ei + E;

    const int NB   = (N + 255) >> BSHIFT;      // buckets
    const int M    = NB * NBLK;                // count-matrix size
    const int TILE = (E + NBLK - 1) / NBLK;
    const int scanB = (M + 1023) / 1024;

    char* w = (char*)d_ws;
    size_t off = 0;
    auto alloc = [&](size_t bytes) -> void* {
        void* p = w + off;
        off = (off + bytes + 255) & ~(size_t)255;
        return p;
    };

    int*      rowptr    = (int*)alloc((size_t)(N + 1) * 4);
    float*    dinv      = (float*)alloc((size_t)N * 4);
    int2*     rec       = (int2*)alloc((size_t)E * 8);
    int2*     staging   = (int2*)alloc((size_t)E * 8);
    int*      cntM      = (int*)alloc((size_t)M * 4);
    int*      offM      = (int*)alloc((size_t)M * 4);
    int*      blockSums = (int*)alloc((size_t)scanB * 4);
    int*      blockOff  = (int*)alloc((size_t)scanB * 4);
    int*      scrTotal  = (int*)alloc(256);
    _Float16* h16       = (_Float16*)alloc((size_t)N * 128 * 2);
    _Float16* act16     = (_Float16*)alloc((size_t)N * 128 * 2);
    float*    pooled    = (float*)alloc((size_t)G * 128 * 4);

    // ---- binned CSR build (once) ----
    binA_count<<<NBLK, 256, 0, stream>>>(dstI, cntM, E, NB, TILE);
    scan1_kernel<<<scanB, 256, 0, stream>>>(cntM, blockSums, M);
    scan_top_kernel<<<1, 1024, 0, stream>>>(blockSums, blockOff, scrTotal, scanB);
    scan2_kernel<<<scanB, 256, 0, stream>>>(cntM, blockOff, offM, M);
    binA_place<<<NBLK, 256, 0, stream>>>(srcI, dstI, offM, staging, E, NB, TILE);
    bucket_rows<<<NB, 256, 0, stream>>>(staging, offM, rowptr, dinv, N, NB, E);
    bucket_scatter<<<NB, 256, 0, stream>>>(staging, offM, rowptr, dinv, rec, N, NB, E);

    const int gemmBlocks = (N + 63) / 64;
    const int gathBlocks = (N * 16 + 255) / 256;

    // ---- layer 1 ----
    gemm_mfma_kernel<1><<<gemmBlocks, 256, 0, stream>>>(x, W1, h16, N);
    gather_kernel<1><<<gathBlocks, 256, 0, stream>>>(rowptr, rec, dinv, h16, b1, act16, N, 1);
    // ---- layer 2 ----
    gemm_mfma_kernel<0><<<gemmBlocks, 256, 0, stream>>>(act16, W2, h16, N);
    gather_kernel<1><<<gathBlocks, 256, 0, stream>>>(rowptr, rec, dinv, h16, b2, act16, N, 1);
    // ---- layer 3 ----
    gemm_mfma_kernel<0><<<gemmBlocks, 256, 0, stream>>>(act16, W3, h16, N);
    gather_kernel<1><<<gathBlocks, 256, 0, stream>>>(rowptr, rec, dinv, h16, b3, act16, N, 0);

    // ---- pool + classify ----
    pool_kernel<<<G, 256, 0, stream>>>(act16, batch, pooled, N);
    final_kernel<<<G, 64, 0, stream>>>(pooled, Wl, bl, out, C);
}